// Round 1
// baseline (631.593 us; speedup 1.0000x reference)
//
#include <hip/hip_runtime.h>
#include <math.h>
#include <stdint.h>

// Problem constants (B=1)
static constexpr int T   = 2048;
static constexpr int D   = 2048;
static constexpr int HQ  = 32;
static constexpr int HKV = 8;
static constexpr int DH  = 64;
static constexpr int DKV = HKV * DH;  // 512

typedef float f32x4 __attribute__((ext_vector_type(4)));
typedef __bf16 bf16x8 __attribute__((ext_vector_type(8)));
typedef unsigned short u16x8 __attribute__((ext_vector_type(8)));

__device__ __forceinline__ unsigned short f2bf(float f) {
  union { float f; unsigned u; } v; v.f = f;
  unsigned u = v.u;
  return (unsigned short)((u + 0x7FFFu + ((u >> 16) & 1u)) >> 16);  // RNE
}
__device__ __forceinline__ float bf2f(unsigned short b) {
  union { unsigned u; float f; } v; v.u = ((unsigned)b) << 16;
  return v.f;
}
__device__ __forceinline__ f32x4 mfma16(u16x8 a, u16x8 b, f32x4 c) {
  return __builtin_amdgcn_mfma_f32_16x16x32_bf16(
      __builtin_bit_cast(bf16x8, a), __builtin_bit_cast(bf16x8, b), c, 0, 0, 0);
}

// ---------------------------------------------------------------- fp32 -> bf16
__global__ __launch_bounds__(256) void cvt_f32_bf16(const float* __restrict__ src,
                                                    unsigned short* __restrict__ dst,
                                                    int n) {
  int i = (blockIdx.x * 256 + threadIdx.x) * 8;
  if (i >= n) return;
  float4 a = *(const float4*)(src + i);
  float4 b = *(const float4*)(src + i + 4);
  u16x8 r = {f2bf(a.x), f2bf(a.y), f2bf(a.z), f2bf(a.w),
             f2bf(b.x), f2bf(b.y), f2bf(b.z), f2bf(b.w)};
  *(u16x8*)(dst + i) = r;
}

// ---------------------------------------------------- C[M,N] = A[M,K] @ Bt[N,K]^T
// bf16 inputs, fp32 accum. 64x64 block tile, 4 waves, each wave = 16 rows x 64 cols.
// MFMA 16x16x32: A-frag A[m=lane&15][k=quad*8+j], B-frag B[k][n=lane&15],
// D row=quad*4+r, col=lane&15  (m89/m91-verified layouts).
template <bool OUT_BF16>
__global__ __launch_bounds__(256) void gemm_bt_bf16(const unsigned short* __restrict__ A,
                                                    const unsigned short* __restrict__ Bt,
                                                    void* __restrict__ Cv,
                                                    int N, int K) {
  const int bn = blockIdx.x * 64, bm = blockIdx.y * 64;
  const int w = threadIdx.x >> 6, lane = threadIdx.x & 63;
  const int c = lane & 15, quad = lane >> 4;
  const unsigned short* ap = A + (size_t)(bm + w * 16 + c) * K + quad * 8;
  const unsigned short* bp = Bt + (size_t)(bn + c) * K + quad * 8;
  f32x4 acc[4] = {{0.f,0.f,0.f,0.f},{0.f,0.f,0.f,0.f},{0.f,0.f,0.f,0.f},{0.f,0.f,0.f,0.f}};
  for (int k0 = 0; k0 < K; k0 += 32) {
    u16x8 a = *(const u16x8*)(ap + k0);
#pragma unroll
    for (int ni = 0; ni < 4; ni++) {
      u16x8 b = *(const u16x8*)(bp + (size_t)ni * 16 * K + k0);
      acc[ni] = mfma16(a, b, acc[ni]);
    }
  }
#pragma unroll
  for (int ni = 0; ni < 4; ni++) {
#pragma unroll
    for (int r = 0; r < 4; r++) {
      size_t row = (size_t)(bm + w * 16 + quad * 4 + r);
      size_t col = (size_t)(bn + ni * 16 + c);
      if (OUT_BF16)
        ((unsigned short*)Cv)[row * N + col] = f2bf(acc[ni][r]);
      else
        ((float*)Cv)[row * N + col] = acc[ni][r];
    }
  }
}

// ------------------------------------------------------------------------ RoPE
// In-place on bf16 Q (T x 2048) and K (T x 512). Pair (2i,2i+1) within each head.
__global__ __launch_bounds__(256) void rope_kernel(unsigned short* __restrict__ Qb,
                                                   unsigned short* __restrict__ Kb,
                                                   const float* __restrict__ cosb,
                                                   const float* __restrict__ sinb) {
  const int QP = T * HQ * (DH / 2);   // 2097152
  const int KP = T * HKV * (DH / 2);  // 524288
  int idx = blockIdx.x * 256 + threadIdx.x;
  if (idx >= QP + KP) return;
  unsigned short* p;
  int t, i;
  if (idx < QP) {
    t = idx / (HQ * DH / 2);
    int rem = idx - t * (HQ * DH / 2);  // h*32 + i
    i = rem & 31;
    p = Qb + (size_t)t * D + rem * 2;   // h*64 + 2i
  } else {
    int j = idx - QP;
    t = j / (HKV * DH / 2);
    int rem = j - t * (HKV * DH / 2);
    i = rem & 31;
    p = Kb + (size_t)t * DKV + rem * 2;
  }
  float x0 = bf2f(p[0]), x1 = bf2f(p[1]);
  float cs = cosb[t * 32 + i], sn = sinb[t * 32 + i];
  p[0] = f2bf(x0 * cs - x1 * sn);
  p[1] = f2bf(x0 * sn + x1 * cs);
}

// ------------------------------------------------------------------- attention
// Flash-style. Block = (q head h, 64-row Q tile). 4 waves, wave w owns q rows
// [qbase+16w, qbase+16w+16). Online softmax; causal at tile + element level.
__global__ __launch_bounds__(256) void attn_kernel(const unsigned short* __restrict__ Q,
                                                   const unsigned short* __restrict__ Kb,
                                                   const unsigned short* __restrict__ Vb,
                                                   unsigned short* __restrict__ Ob) {
  const int h = blockIdx.x, qt = blockIdx.y;
  const int kh = h >> 2;          // GQA: q head h -> kv head h/4
  const int qbase = qt * 64;
  const int tid = threadIdx.x, w = tid >> 6, lane = tid & 63;
  const int c = lane & 15, quad = lane >> 4;

  __shared__ alignas(16) unsigned short Kt[64 * 72];  // (s, dh), pad 8 -> 2-way free
  __shared__ alignas(16) unsigned short Vt[64 * 72];  // (dh, s) transposed
  __shared__ alignas(16) unsigned short Pl[64 * 72];  // P round-trip, per-wave rows

  // Q fragments for this wave's 16 rows (k = dh, 2 k-steps of 32)
  u16x8 qf[2];
  {
    const unsigned short* qp = Q + (size_t)(qbase + w * 16 + c) * D + h * DH + quad * 8;
    qf[0] = *(const u16x8*)qp;
    qf[1] = *(const u16x8*)(qp + 32);
  }

  f32x4 o[4] = {{0.f,0.f,0.f,0.f},{0.f,0.f,0.f,0.f},{0.f,0.f,0.f,0.f},{0.f,0.f,0.f,0.f}};
  float mrow[4] = {-INFINITY, -INFINITY, -INFINITY, -INFINITY};
  float lrow[4] = {0.f, 0.f, 0.f, 0.f};

  const int sr = tid >> 2;          // staging row 0..63
  const int sc = (tid & 3) * 16;    // staging col group

  for (int st = 0; st <= qt; st++) {
    __syncthreads();  // previous-iter Kt/Vt reads done before overwrite
    {
      const unsigned short* kg = Kb + (size_t)(st * 64 + sr) * DKV + kh * DH + sc;
      *(u16x8*)&Kt[sr * 72 + sc] = *(const u16x8*)kg;
      *(u16x8*)&Kt[sr * 72 + sc + 8] = *(const u16x8*)(kg + 8);
      const unsigned short* vg = Vb + (size_t)(st * 64 + sr) * DKV + kh * DH + sc;
      u16x8 v0 = *(const u16x8*)vg, v1 = *(const u16x8*)(vg + 8);
#pragma unroll
      for (int j = 0; j < 8; j++) {
        Vt[(sc + j) * 72 + sr] = v0[j];
        Vt[(sc + 8 + j) * 72 + sr] = v1[j];
      }
    }
    __syncthreads();

    // S = Q K^T : B[k=dh][n=s] = K[s][dh] -> read Kt row (ni*16+c)
    f32x4 sacc[4] = {{0.f,0.f,0.f,0.f},{0.f,0.f,0.f,0.f},{0.f,0.f,0.f,0.f},{0.f,0.f,0.f,0.f}};
#pragma unroll
    for (int ks = 0; ks < 2; ks++) {
      u16x8 qk = qf[ks];
#pragma unroll
      for (int ni = 0; ni < 4; ni++) {
        u16x8 kf = *(const u16x8*)&Kt[(ni * 16 + c) * 72 + ks * 32 + quad * 8];
        sacc[ni] = mfma16(qk, kf, sacc[ni]);
      }
    }

    // Online softmax (per row = quad*4+r; reduce over 16 lanes sharing quad)
    float p[4][4];
#pragma unroll
    for (int r = 0; r < 4; r++) {
      int row = qbase + w * 16 + quad * 4 + r;
      float sv[4];
#pragma unroll
      for (int ni = 0; ni < 4; ni++) {
        float s = sacc[ni][r] * 0.125f;  // 1/sqrt(64)
        int col = st * 64 + ni * 16 + c;
        sv[ni] = (col > row) ? -INFINITY : s;
      }
      float tmax = fmaxf(fmaxf(sv[0], sv[1]), fmaxf(sv[2], sv[3]));
#pragma unroll
      for (int off = 1; off < 16; off <<= 1) tmax = fmaxf(tmax, __shfl_xor(tmax, off, 64));
      float mnew = fmaxf(mrow[r], tmax);
      float alpha = __expf(mrow[r] - mnew);  // 0 when mrow=-inf
      mrow[r] = mnew;
      float psum = 0.f;
#pragma unroll
      for (int ni = 0; ni < 4; ni++) {
        p[ni][r] = __expf(sv[ni] - mnew);
        psum += p[ni][r];
      }
#pragma unroll
      for (int off = 1; off < 16; off <<= 1) psum += __shfl_xor(psum, off, 64);
      lrow[r] = lrow[r] * alpha + psum;
#pragma unroll
      for (int ni = 0; ni < 4; ni++) o[ni][r] *= alpha;
    }

    // P: C-layout -> LDS -> A-layout (per-wave private rows; no barrier needed)
#pragma unroll
    for (int r = 0; r < 4; r++)
#pragma unroll
      for (int ni = 0; ni < 4; ni++)
        Pl[(w * 16 + quad * 4 + r) * 72 + ni * 16 + c] = f2bf(p[ni][r]);

    // O += P V : B[k=s][n=dh] = V[s][dh] = Vt[dh][s] -> read Vt row (ni*16+c)
#pragma unroll
    for (int ks = 0; ks < 2; ks++) {
      u16x8 pf = *(const u16x8*)&Pl[(w * 16 + c) * 72 + ks * 32 + quad * 8];
#pragma unroll
      for (int ni = 0; ni < 4; ni++) {
        u16x8 vf = *(const u16x8*)&Vt[(ni * 16 + c) * 72 + ks * 32 + quad * 8];
        o[ni] = mfma16(pf, vf, o[ni]);
      }
    }
  }

#pragma unroll
  for (int ni = 0; ni < 4; ni++)
#pragma unroll
    for (int r = 0; r < 4; r++) {
      size_t row = (size_t)(qbase + w * 16 + quad * 4 + r);
      size_t col = (size_t)(h * DH + ni * 16 + c);
      Ob[row * D + col] = f2bf(o[ni][r] / lrow[r]);
    }
}

// ------------------------------------------------------------------- launcher
extern "C" void kernel_launch(void* const* d_in, const int* in_sizes, int n_in,
                              void* d_out, int out_size, void* d_ws, size_t ws_size,
                              hipStream_t stream) {
  const float* x  = (const float*)d_in[0];
  const float* Wq = (const float*)d_in[1];
  const float* Wk = (const float*)d_in[2];
  const float* Wv = (const float*)d_in[3];
  const float* Wo = (const float*)d_in[4];
  const float* rc = (const float*)d_in[5];
  const float* rs = (const float*)d_in[6];
  float* out = (float*)d_out;

  char* ws = (char*)d_ws;
  // bf16 workspace layout (bytes). Ab reuses xb (x dead after V GEMM). Total 40 MB.
  unsigned short* xb  = (unsigned short*)(ws);                        // 8 MB (T*D)
  unsigned short* wqb = (unsigned short*)(ws + (size_t)(8u  << 20));  // 8 MB
  unsigned short* wkb = (unsigned short*)(ws + (size_t)(16u << 20));  // 2 MB
  unsigned short* wvb = (unsigned short*)(ws + (size_t)(18u << 20));  // 2 MB
  unsigned short* wob = (unsigned short*)(ws + (size_t)(20u << 20));  // 8 MB
  unsigned short* Qb  = (unsigned short*)(ws + (size_t)(28u << 20));  // 8 MB
  unsigned short* Kb  = (unsigned short*)(ws + (size_t)(36u << 20));  // 2 MB
  unsigned short* Vb  = (unsigned short*)(ws + (size_t)(38u << 20));  // 2 MB
  unsigned short* Ab  = xb;                                           // alias, 8 MB

  cvt_f32_bf16<<<dim3(T * D / 2048),   256, 0, stream>>>(x,  xb,  T * D);
  cvt_f32_bf16<<<dim3(D * D / 2048),   256, 0, stream>>>(Wq, wqb, D * D);
  cvt_f32_bf16<<<dim3(DKV * D / 2048), 256, 0, stream>>>(Wk, wkb, DKV * D);
  cvt_f32_bf16<<<dim3(DKV * D / 2048), 256, 0, stream>>>(Wv, wvb, DKV * D);
  cvt_f32_bf16<<<dim3(D * D / 2048),   256, 0, stream>>>(Wo, wob, D * D);

  gemm_bt_bf16<true><<<dim3(D / 64,   T / 64), 256, 0, stream>>>(xb, wqb, Qb, D,   D);
  gemm_bt_bf16<true><<<dim3(DKV / 64, T / 64), 256, 0, stream>>>(xb, wkb, Kb, DKV, D);
  gemm_bt_bf16<true><<<dim3(DKV / 64, T / 64), 256, 0, stream>>>(xb, wvb, Vb, DKV, D);

  {
    int pairs = T * HQ * (DH / 2) + T * HKV * (DH / 2);
    rope_kernel<<<dim3((pairs + 255) / 256), 256, 0, stream>>>(Qb, Kb, rc, rs);
  }

  attn_kernel<<<dim3(HQ, T / 64), 256, 0, stream>>>(Qb, Kb, Vb, Ab);

  gemm_bt_bf16<false><<<dim3(D / 64, T / 64), 256, 0, stream>>>(Ab, wob, out, D, D);
}

// Round 2
// 304.277 us; speedup vs baseline: 2.0757x; 2.0757x over previous
//
#include <hip/hip_runtime.h>
#include <math.h>
#include <stdint.h>

// Problem constants (B=1)
static constexpr int T   = 2048;
static constexpr int D   = 2048;
static constexpr int HQ  = 32;
static constexpr int HKV = 8;
static constexpr int DH  = 64;
static constexpr int DKV = HKV * DH;       // 512
static constexpr int NQKV = D + 2 * DKV;   // 3072 fused QKV output width

typedef float f32x4 __attribute__((ext_vector_type(4)));
typedef __bf16 bf16x8 __attribute__((ext_vector_type(8)));
typedef unsigned short u16x8 __attribute__((ext_vector_type(8)));

__device__ __forceinline__ unsigned short f2bf(float f) {
  union { float f; unsigned u; } v; v.f = f;
  unsigned u = v.u;
  return (unsigned short)((u + 0x7FFFu + ((u >> 16) & 1u)) >> 16);  // RNE
}
__device__ __forceinline__ float bf2f(unsigned short b) {
  union { unsigned u; float f; } v; v.u = ((unsigned)b) << 16;
  return v.f;
}
__device__ __forceinline__ f32x4 mfma16(u16x8 a, u16x8 b, f32x4 c) {
  return __builtin_amdgcn_mfma_f32_16x16x32_bf16(
      __builtin_bit_cast(bf16x8, a), __builtin_bit_cast(bf16x8, b), c, 0, 0, 0);
}
// async global->LDS, 16B per lane. LDS dest is wave-uniform base + lane*16.
__device__ __forceinline__ void gld16(const unsigned short* g, unsigned short* l) {
  __builtin_amdgcn_global_load_lds(
      (const __attribute__((address_space(1))) unsigned*)g,
      (__attribute__((address_space(3))) unsigned*)l, 16, 0, 0);
}

// ---------------------------------------------------------------- fp32 -> bf16
__global__ __launch_bounds__(256) void cvt_f32_bf16(const float* __restrict__ src,
                                                    unsigned short* __restrict__ dst,
                                                    int n) {
  int i = (blockIdx.x * 256 + threadIdx.x) * 8;
  if (i >= n) return;
  float4 a = *(const float4*)(src + i);
  float4 b = *(const float4*)(src + i + 4);
  u16x8 r = {f2bf(a.x), f2bf(a.y), f2bf(a.z), f2bf(a.w),
             f2bf(b.x), f2bf(b.y), f2bf(b.z), f2bf(b.w)};
  *(u16x8*)(dst + i) = r;
}

// ---------------------------------------------------- C[M,N] = A[M,K] @ Bt[N,K]^T
// m97 structure: 128x128 block tile, BK=64, async global_load_lds (16B),
// XOR-swizzled LDS (chunk slot = chunk ^ (row&7)) so fragment ds_read_b128 is
// 2-way-bank-aliased only (free, m136). 4 waves in 2x2; each wave 64x64 via
// 4x4 grid of 16x16x32 MFMA. Layouts per m89/m91: A[m=lane&15][k=quad*8+j],
// B[k][n=lane&15], D row=quad*4+r col=lane&15.
template <bool OUT_BF16>
__global__ __launch_bounds__(256) void gemm_bt_bf16(const unsigned short* __restrict__ A,
                                                    const unsigned short* __restrict__ Bt,
                                                    void* __restrict__ Cv,
                                                    int N, int K) {
  __shared__ alignas(16) unsigned short As[128 * 64];  // 16 KB, row-major K-chunks swizzled
  __shared__ alignas(16) unsigned short Bs[128 * 64];  // 16 KB

  const int bn = blockIdx.x * 128, bm = blockIdx.y * 128;
  const int tid = threadIdx.x, w = tid >> 6, lane = tid & 63;
  const int c = lane & 15, quad = lane >> 4;
  const int wm = w >> 1, wn = w & 1;

  // staging: wave w owns 32 rows of A-tile and 32 rows of B-tile.
  // lane -> (row-in-8-group, swizzled source chunk); LDS slot = lane order.
  const int rig = lane >> 3;                  // 0..7
  const int sch = (lane & 7) ^ rig;           // source k-chunk (self-inverse XOR)
  const size_t laneOff = (size_t)rig * K + sch * 8;
  const unsigned short* aBase = A + (size_t)(bm + w * 32) * K + laneOff;
  const unsigned short* bBase = Bt + (size_t)(bn + w * 32) * K + laneOff;
  unsigned short* AsW = As + (w * 32) * 64;
  unsigned short* BsW = Bs + (w * 32) * 64;

  f32x4 acc[4][4] = {};

  for (int k0 = 0; k0 < K; k0 += 64) {
#pragma unroll
    for (int j = 0; j < 4; j++) {
      gld16(aBase + (size_t)(j * 8) * K + k0, AsW + j * 8 * 64);
      gld16(bBase + (size_t)(j * 8) * K + k0, BsW + j * 8 * 64);
    }
    __syncthreads();  // drains vmcnt -> LDS tiles complete

#pragma unroll
    for (int ks = 0; ks < 2; ks++) {
      const int slot = (ks * 4 + quad) ^ (c & 7);
      u16x8 a[4], b[4];
#pragma unroll
      for (int mi = 0; mi < 4; mi++)
        a[mi] = *(const u16x8*)&As[(wm * 64 + mi * 16 + c) * 64 + slot * 8];
#pragma unroll
      for (int ni = 0; ni < 4; ni++)
        b[ni] = *(const u16x8*)&Bs[(wn * 64 + ni * 16 + c) * 64 + slot * 8];
#pragma unroll
      for (int mi = 0; mi < 4; mi++)
#pragma unroll
        for (int ni = 0; ni < 4; ni++)
          acc[mi][ni] = mfma16(a[mi], b[ni], acc[mi][ni]);
    }
    __syncthreads();  // protect LDS from next-iter overwrite
  }

#pragma unroll
  for (int mi = 0; mi < 4; mi++)
#pragma unroll
    for (int ni = 0; ni < 4; ni++)
#pragma unroll
      for (int r = 0; r < 4; r++) {
        size_t row = (size_t)(bm + wm * 64 + mi * 16 + quad * 4 + r);
        size_t col = (size_t)(bn + wn * 64 + ni * 16 + c);
        if (OUT_BF16)
          ((unsigned short*)Cv)[row * N + col] = f2bf(acc[mi][ni][r]);
        else
          ((float*)Cv)[row * N + col] = acc[mi][ni][r];
      }
}

// ------------------------------------------------------------------------ RoPE
// In-place on fused QKV bf16 buffer (T x 3072): Q cols [0,2048), K cols [2048,2560).
__global__ __launch_bounds__(256) void rope_kernel(unsigned short* __restrict__ QKV,
                                                   const float* __restrict__ cosb,
                                                   const float* __restrict__ sinb) {
  const int QP = T * HQ * (DH / 2);   // 2097152
  const int KP = T * HKV * (DH / 2);  // 524288
  int idx = blockIdx.x * 256 + threadIdx.x;
  if (idx >= QP + KP) return;
  unsigned short* p;
  int t, i;
  if (idx < QP) {
    t = idx / (HQ * DH / 2);
    int rem = idx - t * (HQ * DH / 2);  // h*32 + i
    i = rem & 31;
    p = QKV + (size_t)t * NQKV + rem * 2;
  } else {
    int j = idx - QP;
    t = j / (HKV * DH / 2);
    int rem = j - t * (HKV * DH / 2);
    i = rem & 31;
    p = QKV + (size_t)t * NQKV + D + rem * 2;
  }
  float x0 = bf2f(p[0]), x1 = bf2f(p[1]);
  float cs = cosb[t * 32 + i], sn = sinb[t * 32 + i];
  p[0] = f2bf(x0 * cs - x1 * sn);
  p[1] = f2bf(x0 * sn + x1 * cs);
}

// ------------------------------------------------------------------- attention
// Flash-style. Block = (q head h, 64-row Q tile). 4 waves, wave w owns q rows
// [qbase+16w, qbase+16w+16). Q/K/V live in fused QKV buffer, row stride 3072.
__global__ __launch_bounds__(256) void attn_kernel(const unsigned short* __restrict__ QKV,
                                                   unsigned short* __restrict__ Ob) {
  const int h = blockIdx.x, qt = blockIdx.y;
  const int kh = h >> 2;          // GQA: q head h -> kv head h/4
  const int qbase = qt * 64;
  const int tid = threadIdx.x, w = tid >> 6, lane = tid & 63;
  const int c = lane & 15, quad = lane >> 4;

  const unsigned short* Q  = QKV;                 // stride NQKV
  const unsigned short* Kb = QKV + D;             // stride NQKV
  const unsigned short* Vb = QKV + D + DKV;       // stride NQKV

  __shared__ alignas(16) unsigned short Kt[64 * 72];  // (s, dh), pad 8 -> 2-way free
  __shared__ alignas(16) unsigned short Vt[64 * 72];  // (dh, s) transposed
  __shared__ alignas(16) unsigned short Pl[64 * 72];  // P round-trip, per-wave rows

  // Q fragments for this wave's 16 rows (k = dh, 2 k-steps of 32)
  u16x8 qf[2];
  {
    const unsigned short* qp = Q + (size_t)(qbase + w * 16 + c) * NQKV + h * DH + quad * 8;
    qf[0] = *(const u16x8*)qp;
    qf[1] = *(const u16x8*)(qp + 32);
  }

  f32x4 o[4] = {};
  float mrow[4] = {-INFINITY, -INFINITY, -INFINITY, -INFINITY};
  float lrow[4] = {0.f, 0.f, 0.f, 0.f};

  const int sr = tid >> 2;          // staging row 0..63
  const int sc = (tid & 3) * 16;    // staging col group

  for (int st = 0; st <= qt; st++) {
    __syncthreads();  // previous-iter Kt/Vt reads done before overwrite
    {
      const unsigned short* kg = Kb + (size_t)(st * 64 + sr) * NQKV + kh * DH + sc;
      *(u16x8*)&Kt[sr * 72 + sc] = *(const u16x8*)kg;
      *(u16x8*)&Kt[sr * 72 + sc + 8] = *(const u16x8*)(kg + 8);
      const unsigned short* vg = Vb + (size_t)(st * 64 + sr) * NQKV + kh * DH + sc;
      u16x8 v0 = *(const u16x8*)vg, v1 = *(const u16x8*)(vg + 8);
#pragma unroll
      for (int j = 0; j < 8; j++) {
        Vt[(sc + j) * 72 + sr] = v0[j];
        Vt[(sc + 8 + j) * 72 + sr] = v1[j];
      }
    }
    __syncthreads();

    // S = Q K^T : B[k=dh][n=s] = K[s][dh] -> read Kt row (ni*16+c)
    f32x4 sacc[4] = {};
#pragma unroll
    for (int ks = 0; ks < 2; ks++) {
      u16x8 qk = qf[ks];
#pragma unroll
      for (int ni = 0; ni < 4; ni++) {
        u16x8 kf = *(const u16x8*)&Kt[(ni * 16 + c) * 72 + ks * 32 + quad * 8];
        sacc[ni] = mfma16(qk, kf, sacc[ni]);
      }
    }

    // Online softmax (per row = quad*4+r; reduce over 16 lanes sharing quad)
    float p[4][4];
#pragma unroll
    for (int r = 0; r < 4; r++) {
      int row = qbase + w * 16 + quad * 4 + r;
      float sv[4];
#pragma unroll
      for (int ni = 0; ni < 4; ni++) {
        float s = sacc[ni][r] * 0.125f;  // 1/sqrt(64)
        int col = st * 64 + ni * 16 + c;
        sv[ni] = (col > row) ? -INFINITY : s;
      }
      float tmax = fmaxf(fmaxf(sv[0], sv[1]), fmaxf(sv[2], sv[3]));
#pragma unroll
      for (int off = 1; off < 16; off <<= 1) tmax = fmaxf(tmax, __shfl_xor(tmax, off, 64));
      float mnew = fmaxf(mrow[r], tmax);
      float alpha = __expf(mrow[r] - mnew);  // 0 when mrow=-inf
      mrow[r] = mnew;
      float psum = 0.f;
#pragma unroll
      for (int ni = 0; ni < 4; ni++) {
        p[ni][r] = __expf(sv[ni] - mnew);
        psum += p[ni][r];
      }
#pragma unroll
      for (int off = 1; off < 16; off <<= 1) psum += __shfl_xor(psum, off, 64);
      lrow[r] = lrow[r] * alpha + psum;
#pragma unroll
      for (int ni = 0; ni < 4; ni++) o[ni][r] *= alpha;
    }

    // P: C-layout -> LDS -> A-layout (per-wave private rows; no barrier needed)
#pragma unroll
    for (int r = 0; r < 4; r++)
#pragma unroll
      for (int ni = 0; ni < 4; ni++)
        Pl[(w * 16 + quad * 4 + r) * 72 + ni * 16 + c] = f2bf(p[ni][r]);

    // O += P V : B[k=s][n=dh] = V[s][dh] = Vt[dh][s] -> read Vt row (ni*16+c)
#pragma unroll
    for (int ks = 0; ks < 2; ks++) {
      u16x8 pf = *(const u16x8*)&Pl[(w * 16 + c) * 72 + ks * 32 + quad * 8];
#pragma unroll
      for (int ni = 0; ni < 4; ni++) {
        u16x8 vf = *(const u16x8*)&Vt[(ni * 16 + c) * 72 + ks * 32 + quad * 8];
        o[ni] = mfma16(pf, vf, o[ni]);
      }
    }
  }

#pragma unroll
  for (int ni = 0; ni < 4; ni++)
#pragma unroll
    for (int r = 0; r < 4; r++) {
      size_t row = (size_t)(qbase + w * 16 + quad * 4 + r);
      size_t col = (size_t)(h * DH + ni * 16 + c);
      Ob[row * D + col] = f2bf(o[ni][r] / lrow[r]);
    }
}

// ------------------------------------------------------------------- launcher
extern "C" void kernel_launch(void* const* d_in, const int* in_sizes, int n_in,
                              void* d_out, int out_size, void* d_ws, size_t ws_size,
                              hipStream_t stream) {
  const float* x  = (const float*)d_in[0];
  const float* Wq = (const float*)d_in[1];
  const float* Wk = (const float*)d_in[2];
  const float* Wv = (const float*)d_in[3];
  const float* Wo = (const float*)d_in[4];
  const float* rc = (const float*)d_in[5];
  const float* rs = (const float*)d_in[6];
  float* out = (float*)d_out;

  char* ws = (char*)d_ws;
  // bf16 workspace (bytes):
  //   xb    8 MB  (T*D)          [aliased by Ab after QKV GEMM consumes x]
  //   wqkv 12 MB  (3072*2048)    rows: Wq[0,2048) Wk[2048,2560) Wv[2560,3072)
  //   wob   8 MB  (2048*2048)
  //   qkvb 12 MB  (2048*3072)
  unsigned short* xb   = (unsigned short*)(ws);
  unsigned short* wqkv = (unsigned short*)(ws + (size_t)(8u  << 20));
  unsigned short* wob  = (unsigned short*)(ws + (size_t)(20u << 20));
  unsigned short* qkvb = (unsigned short*)(ws + (size_t)(28u << 20));
  unsigned short* Ab   = xb;  // alias

  cvt_f32_bf16<<<dim3(T * D / 2048),   256, 0, stream>>>(x,  xb, T * D);
  cvt_f32_bf16<<<dim3(D * D / 2048),   256, 0, stream>>>(Wq, wqkv, D * D);
  cvt_f32_bf16<<<dim3(DKV * D / 2048), 256, 0, stream>>>(Wk, wqkv + (size_t)D * D, DKV * D);
  cvt_f32_bf16<<<dim3(DKV * D / 2048), 256, 0, stream>>>(Wv, wqkv + (size_t)(D + DKV) * D, DKV * D);
  cvt_f32_bf16<<<dim3(D * D / 2048),   256, 0, stream>>>(Wo, wob, D * D);

  // Fused QKV projection: (2048 x 3072) = x (2048x2048) @ Wqkv^T
  gemm_bt_bf16<true><<<dim3(NQKV / 128, T / 128), 256, 0, stream>>>(xb, wqkv, qkvb, NQKV, D);

  {
    int pairs = T * HQ * (DH / 2) + T * HKV * (DH / 2);
    rope_kernel<<<dim3((pairs + 255) / 256), 256, 0, stream>>>(qkvb, rc, rs);
  }

  attn_kernel<<<dim3(HQ, T / 64), 256, 0, stream>>>(qkvb, Ab);

  // Output projection: (2048 x 2048) = Ab @ Wo^T, fp32 out
  gemm_bt_bf16<false><<<dim3(D / 128, T / 128), 256, 0, stream>>>(Ab, wob, out, D, D);
}

// Round 3
// 265.346 us; speedup vs baseline: 2.3803x; 1.1467x over previous
//
#include <hip/hip_runtime.h>
#include <math.h>
#include <stdint.h>

// Problem constants (B=1)
static constexpr int T   = 2048;
static constexpr int D   = 2048;
static constexpr int HQ  = 32;
static constexpr int HKV = 8;
static constexpr int DH  = 64;
static constexpr int DKV = HKV * DH;       // 512
static constexpr int NQKV = D + 2 * DKV;   // 3072 fused QKV output width

typedef float f32x4 __attribute__((ext_vector_type(4)));
typedef __bf16 bf16x8 __attribute__((ext_vector_type(8)));
typedef unsigned short u16x8 __attribute__((ext_vector_type(8)));
typedef unsigned short u16x4 __attribute__((ext_vector_type(4)));

__device__ __forceinline__ unsigned short f2bf(float f) {
  union { float f; unsigned u; } v; v.f = f;
  unsigned u = v.u;
  return (unsigned short)((u + 0x7FFFu + ((u >> 16) & 1u)) >> 16);  // RNE
}
__device__ __forceinline__ float bf2f(unsigned short b) {
  union { unsigned u; float f; } v; v.u = ((unsigned)b) << 16;
  return v.f;
}
__device__ __forceinline__ f32x4 mfma16(u16x8 a, u16x8 b, f32x4 c) {
  return __builtin_amdgcn_mfma_f32_16x16x32_bf16(
      __builtin_bit_cast(bf16x8, a), __builtin_bit_cast(bf16x8, b), c, 0, 0, 0);
}
// async global->LDS, 16B per lane. LDS dest is wave-uniform base + lane*16.
__device__ __forceinline__ void gld16(const unsigned short* g, unsigned short* l) {
  __builtin_amdgcn_global_load_lds(
      (const __attribute__((address_space(1))) unsigned*)g,
      (__attribute__((address_space(3))) unsigned*)l, 16, 0, 0);
}

// ---------------------------------------------------------------- fp32 -> bf16
__global__ __launch_bounds__(256) void cvt_f32_bf16(const float* __restrict__ src,
                                                    unsigned short* __restrict__ dst,
                                                    int n) {
  int i = (blockIdx.x * 256 + threadIdx.x) * 8;
  if (i >= n) return;
  float4 a = *(const float4*)(src + i);
  float4 b = *(const float4*)(src + i + 4);
  u16x8 r = {f2bf(a.x), f2bf(a.y), f2bf(a.z), f2bf(a.w),
             f2bf(b.x), f2bf(b.y), f2bf(b.z), f2bf(b.w)};
  *(u16x8*)(dst + i) = r;
}

// ---------------------------------------------------- C[M,N] = A[M,K] @ Bt[N,K]^T
// m97 structure: 128x128 block tile, BK=64, async global_load_lds (16B),
// XOR-swizzled LDS (chunk slot = chunk ^ (row&7)). 4 waves in 2x2; each wave
// 64x64 via 4x4 grid of 16x16x32 MFMA.
template <bool OUT_BF16>
__global__ __launch_bounds__(256) void gemm_bt_bf16(const unsigned short* __restrict__ A,
                                                    const unsigned short* __restrict__ Bt,
                                                    void* __restrict__ Cv,
                                                    int N, int K) {
  __shared__ alignas(16) unsigned short As[128 * 64];  // 16 KB
  __shared__ alignas(16) unsigned short Bs[128 * 64];  // 16 KB

  const int bn = blockIdx.x * 128, bm = blockIdx.y * 128;
  const int tid = threadIdx.x, w = tid >> 6, lane = tid & 63;
  const int c = lane & 15, quad = lane >> 4;
  const int wm = w >> 1, wn = w & 1;

  const int rig = lane >> 3;                  // 0..7
  const int sch = (lane & 7) ^ rig;           // source k-chunk (self-inverse XOR)
  const size_t laneOff = (size_t)rig * K + sch * 8;
  const unsigned short* aBase = A + (size_t)(bm + w * 32) * K + laneOff;
  const unsigned short* bBase = Bt + (size_t)(bn + w * 32) * K + laneOff;
  unsigned short* AsW = As + (w * 32) * 64;
  unsigned short* BsW = Bs + (w * 32) * 64;

  f32x4 acc[4][4] = {};

  for (int k0 = 0; k0 < K; k0 += 64) {
#pragma unroll
    for (int j = 0; j < 4; j++) {
      gld16(aBase + (size_t)(j * 8) * K + k0, AsW + j * 8 * 64);
      gld16(bBase + (size_t)(j * 8) * K + k0, BsW + j * 8 * 64);
    }
    __syncthreads();

#pragma unroll
    for (int ks = 0; ks < 2; ks++) {
      const int slot = (ks * 4 + quad) ^ (c & 7);
      u16x8 a[4], b[4];
#pragma unroll
      for (int mi = 0; mi < 4; mi++)
        a[mi] = *(const u16x8*)&As[(wm * 64 + mi * 16 + c) * 64 + slot * 8];
#pragma unroll
      for (int ni = 0; ni < 4; ni++)
        b[ni] = *(const u16x8*)&Bs[(wn * 64 + ni * 16 + c) * 64 + slot * 8];
#pragma unroll
      for (int mi = 0; mi < 4; mi++)
#pragma unroll
        for (int ni = 0; ni < 4; ni++)
          acc[mi][ni] = mfma16(a[mi], b[ni], acc[mi][ni]);
    }
    __syncthreads();
  }

#pragma unroll
  for (int mi = 0; mi < 4; mi++)
#pragma unroll
    for (int ni = 0; ni < 4; ni++)
#pragma unroll
      for (int r = 0; r < 4; r++) {
        size_t row = (size_t)(bm + wm * 64 + mi * 16 + quad * 4 + r);
        size_t col = (size_t)(bn + wn * 64 + ni * 16 + c);
        if (OUT_BF16)
          ((unsigned short*)Cv)[row * N + col] = f2bf(acc[mi][ni][r]);
        else
          ((float*)Cv)[row * N + col] = acc[mi][ni][r];
      }
}

// ------------------------------------------------------------------------ RoPE
// In-place on fused QKV buffer. Q additionally pre-scaled by 1/8 (= 1/sqrt(DH),
// exact pow2) so attention needs no per-score scaling.
__global__ __launch_bounds__(256) void rope_kernel(unsigned short* __restrict__ QKV,
                                                   const float* __restrict__ cosb,
                                                   const float* __restrict__ sinb) {
  const int QP = T * HQ * (DH / 2);   // 2097152
  const int KP = T * HKV * (DH / 2);  // 524288
  int idx = blockIdx.x * 256 + threadIdx.x;
  if (idx >= QP + KP) return;
  unsigned short* p;
  int t, i;
  float sc;
  if (idx < QP) {
    t = idx / (HQ * DH / 2);
    int rem = idx - t * (HQ * DH / 2);
    i = rem & 31;
    p = QKV + (size_t)t * NQKV + rem * 2;
    sc = 0.125f;
  } else {
    int j = idx - QP;
    t = j / (HKV * DH / 2);
    int rem = j - t * (HKV * DH / 2);
    i = rem & 31;
    p = QKV + (size_t)t * NQKV + D + rem * 2;
    sc = 1.0f;
  }
  float x0 = bf2f(p[0]), x1 = bf2f(p[1]);
  float cs = cosb[t * 32 + i], sn = sinb[t * 32 + i];
  p[0] = f2bf((x0 * cs - x1 * sn) * sc);
  p[1] = f2bf((x0 * sn + x1 * cs) * sc);
}

// ------------------------------------------------- V transpose: (T,dkv) -> (dkv,T)
// 64x64 LDS tile, coalesced both sides, pad 65 -> conflict-free.
__global__ __launch_bounds__(256) void transpose_v(const unsigned short* __restrict__ QKV,
                                                   unsigned short* __restrict__ VT) {
  __shared__ unsigned short Ts[64][65];
  const int tb = blockIdx.x, db = blockIdx.y;
  const int tid = threadIdx.x;
  const int r = tid >> 2, c0 = (tid & 3) * 16;
  const unsigned short* src = QKV + (size_t)(tb * 64 + r) * NQKV + (D + DKV) + db * 64 + c0;
  *(u16x8*)&Ts[r][c0]     = *(const u16x8*)src;
  *(u16x8*)&Ts[r][c0 + 8] = *(const u16x8*)(src + 8);
  __syncthreads();
  u16x8 a, b;
#pragma unroll
  for (int j = 0; j < 8; j++) a[j] = Ts[c0 + j][r];
#pragma unroll
  for (int j = 0; j < 8; j++) b[j] = Ts[c0 + 8 + j][r];
  unsigned short* dst = VT + (size_t)(db * 64 + r) * T + tb * 64 + c0;
  *(u16x8*)dst = a;
  *(u16x8*)(dst + 8) = b;
}

// ------------------------------------------------------------------- attention
// Flash-style, S^T formulation. Block = (q head, 32-row Q tile), 2 waves; wave w
// owns q rows [qbase+16w, qbase+16w+16), one q-row per lane-c (m/l/alpha scalar).
// K and V^T tiles staged via global_load_lds with XOR swizzle (conflict-free).
// LPT: longest q-tiles launch first. Only the diagonal tile is masked.
__global__ __launch_bounds__(128) void attn_kernel(const unsigned short* __restrict__ QKV,
                                                   const unsigned short* __restrict__ VT,
                                                   unsigned short* __restrict__ Ob) {
  const int h = blockIdx.x;
  const int qt = (int)(gridDim.y - 1 - blockIdx.y);   // LPT: long tiles first
  const int kh = h >> 2;                              // GQA
  const int qbase = qt * 32;
  const int tid = threadIdx.x, w = tid >> 6, lane = tid & 63;
  const int c = lane & 15, quad = lane >> 4;

  __shared__ alignas(16) unsigned short Kt[64 * 64];   // (key, dh) swizzled
  __shared__ alignas(16) unsigned short Vt[64 * 64];   // (dh, key) swizzled
  __shared__ alignas(16) unsigned short Pb[2 * 16 * 72];  // per-wave P (q, key)

  unsigned short* PbW = Pb + w * 16 * 72;

  // Q as B-fragments (one q-row per lane-c; pre-scaled by 1/8 in rope)
  u16x8 qf[2];
  {
    const unsigned short* qp = QKV + (size_t)(qbase + w * 16 + c) * NQKV + h * DH + quad * 8;
    qf[0] = *(const u16x8*)qp;
    qf[1] = *(const u16x8*)(qp + 32);
  }

  // staging: per wave 32 rows of each tile, 4 gld16 calls of 8 rows each.
  const int srow = lane >> 3;          // row within 8-row group
  const int sch  = (lane & 7) ^ srow;  // swizzled source chunk
  const unsigned short* kgBase = QKV + D + (size_t)(w * 32 + srow) * NQKV + kh * DH + sch * 8;
  const unsigned short* vgBase = VT + (size_t)(kh * DH + w * 32 + srow) * T + sch * 8;
  unsigned short* KtW = Kt + (w * 32) * 64;
  unsigned short* VtW = Vt + (w * 32) * 64;

  f32x4 o[4] = {};
  float m = -INFINITY, l = 0.f;

  const int nFull = qt >> 1;  // tiles 0..nFull-1 need no mask; nFull is diagonal
  for (int st = 0; st <= nFull; st++) {
    __syncthreads();  // previous-iter reads done before overwrite
#pragma unroll
    for (int j = 0; j < 4; j++) {
      gld16(kgBase + ((size_t)st * 64 + (size_t)j * 8) * NQKV, KtW + j * 8 * 64);
      gld16(vgBase + (size_t)j * 8 * T + st * 64, VtW + j * 8 * 64);
    }
    __syncthreads();  // vmcnt drained -> tiles complete

    // S^T = K Q^T : A-frag = K rows, B-frag = Q rows. D[key=quad*4+r][q=c].
    f32x4 sacc[4] = {};
#pragma unroll
    for (int ks = 0; ks < 2; ks++) {
#pragma unroll
      for (int ni = 0; ni < 4; ni++) {
        const int slot = (ks * 4 + quad) ^ (c & 7);
        u16x8 kf = *(const u16x8*)&Kt[(ni * 16 + c) * 64 + slot * 8];
        sacc[ni] = mfma16(kf, qf[ks], sacc[ni]);
      }
    }

    // causal mask: only diagonal tile (uniform branch)
    if (st == nFull) {
      const int qrow = qbase + w * 16 + c;
#pragma unroll
      for (int ni = 0; ni < 4; ni++)
#pragma unroll
        for (int r = 0; r < 4; r++) {
          int key = st * 64 + ni * 16 + quad * 4 + r;
          if (key > qrow) sacc[ni][r] = -INFINITY;
        }
    }

    // online softmax: per-lane scalar m/l (q=c); reduce local 16 + cross-quad.
    float tmax = sacc[0][0];
#pragma unroll
    for (int ni = 0; ni < 4; ni++)
#pragma unroll
      for (int r = 0; r < 4; r++) tmax = fmaxf(tmax, sacc[ni][r]);
    tmax = fmaxf(tmax, __shfl_xor(tmax, 16, 64));
    tmax = fmaxf(tmax, __shfl_xor(tmax, 32, 64));
    float mnew = fmaxf(m, tmax);
    float alpha = __expf(m - mnew);  // exp(-inf)=0 on first tile
    m = mnew;

    float psum = 0.f;
    u16x4 pk[4];
#pragma unroll
    for (int ni = 0; ni < 4; ni++) {
#pragma unroll
      for (int r = 0; r < 4; r++) {
        float p = __expf(sacc[ni][r] - mnew);
        psum += p;
        pk[ni][r] = f2bf(p);
      }
    }
    psum += __shfl_xor(psum, 16, 64);
    psum += __shfl_xor(psum, 32, 64);
    l = l * alpha + psum;

    // P^T (C-layout) -> P (q,key) rows in per-wave LDS: lane writes row c.
#pragma unroll
    for (int ni = 0; ni < 4; ni++)
      *(u16x4*)&PbW[c * 72 + ni * 16 + quad * 4] = pk[ni];

    // broadcast alpha to O's C-layout rows (uniform across quads) and rescale O
    float aR[4];
#pragma unroll
    for (int r = 0; r < 4; r++) aR[r] = __shfl(alpha, quad * 4 + r, 64);
#pragma unroll
    for (int ni = 0; ni < 4; ni++)
#pragma unroll
      for (int r = 0; r < 4; r++) o[ni][r] *= aR[r];

    // O += P V : A-frag = P rows (own-wave LDS region, no barrier needed),
    // B-frag = V^T rows. D[q=quad*4+r][dh=ni*16+c].
#pragma unroll
    for (int ks = 0; ks < 2; ks++) {
      u16x8 pf = *(const u16x8*)&PbW[c * 72 + ks * 32 + quad * 8];
#pragma unroll
      for (int ni = 0; ni < 4; ni++) {
        const int slot = (ks * 4 + quad) ^ (c & 7);
        u16x8 vf = *(const u16x8*)&Vt[(ni * 16 + c) * 64 + slot * 8];
        o[ni] = mfma16(pf, vf, o[ni]);
      }
    }
  }

  float lR[4];
#pragma unroll
  for (int r = 0; r < 4; r++) lR[r] = __shfl(l, quad * 4 + r, 64);
#pragma unroll
  for (int ni = 0; ni < 4; ni++)
#pragma unroll
    for (int r = 0; r < 4; r++) {
      size_t row = (size_t)(qbase + w * 16 + quad * 4 + r);
      size_t col = (size_t)(h * DH + ni * 16 + c);
      Ob[row * D + col] = f2bf(o[ni][r] / lR[r]);
    }
}

// ------------------------------------------------------------------- launcher
extern "C" void kernel_launch(void* const* d_in, const int* in_sizes, int n_in,
                              void* d_out, int out_size, void* d_ws, size_t ws_size,
                              hipStream_t stream) {
  const float* x  = (const float*)d_in[0];
  const float* Wq = (const float*)d_in[1];
  const float* Wk = (const float*)d_in[2];
  const float* Wv = (const float*)d_in[3];
  const float* Wo = (const float*)d_in[4];
  const float* rc = (const float*)d_in[5];
  const float* rs = (const float*)d_in[6];
  float* out = (float*)d_out;

  char* ws = (char*)d_ws;
  // bf16 workspace (bytes):
  //   xb    [0,8M)    x bf16; dead after QKV GEMM -> aliased by Ab
  //   wqkv  [8,20M)   fused QKV weights; dead after QKV GEMM -> VT reuses [8,10M)
  //   wob   [20,28M)
  //   qkvb  [28,40M)
  unsigned short* xb   = (unsigned short*)(ws);
  unsigned short* wqkv = (unsigned short*)(ws + (size_t)(8u  << 20));
  unsigned short* wob  = (unsigned short*)(ws + (size_t)(20u << 20));
  unsigned short* qkvb = (unsigned short*)(ws + (size_t)(28u << 20));
  unsigned short* Ab   = xb;                    // alias (x dead)
  unsigned short* VT   = wqkv;                  // alias (wqkv dead), 2 MB

  cvt_f32_bf16<<<dim3(T * D / 2048),   256, 0, stream>>>(x,  xb, T * D);
  cvt_f32_bf16<<<dim3(D * D / 2048),   256, 0, stream>>>(Wq, wqkv, D * D);
  cvt_f32_bf16<<<dim3(DKV * D / 2048), 256, 0, stream>>>(Wk, wqkv + (size_t)D * D, DKV * D);
  cvt_f32_bf16<<<dim3(DKV * D / 2048), 256, 0, stream>>>(Wv, wqkv + (size_t)(D + DKV) * D, DKV * D);
  cvt_f32_bf16<<<dim3(D * D / 2048),   256, 0, stream>>>(Wo, wob, D * D);

  // Fused QKV projection: (2048 x 3072) = x @ Wqkv^T
  gemm_bt_bf16<true><<<dim3(NQKV / 128, T / 128), 256, 0, stream>>>(xb, wqkv, qkvb, NQKV, D);

  {
    int pairs = T * HQ * (DH / 2) + T * HKV * (DH / 2);
    rope_kernel<<<dim3((pairs + 255) / 256), 256, 0, stream>>>(qkvb, rc, rs);
  }

  // V^T (512 x 2048) for attention B-fragments
  transpose_v<<<dim3(T / 64, DKV / 64), 256, 0, stream>>>(qkvb, VT);

  attn_kernel<<<dim3(HQ, T / 32), 128, 0, stream>>>(qkvb, VT, Ab);

  // Output projection: (2048 x 2048) = Ab @ Wo^T, fp32 out
  gemm_bt_bf16<false><<<dim3(D / 128, T / 128), 256, 0, stream>>>(Ab, wob, out, D, D);
}

// Round 4
// 243.713 us; speedup vs baseline: 2.5915x; 1.0888x over previous
//
#include <hip/hip_runtime.h>
#include <math.h>
#include <stdint.h>

// Problem constants (B=1)
static constexpr int T   = 2048;
static constexpr int D   = 2048;
static constexpr int HQ  = 32;
static constexpr int HKV = 8;
static constexpr int DH  = 64;
static constexpr int DKV = HKV * DH;       // 512
static constexpr int NQKV = D + 2 * DKV;   // 3072 fused QKV output width

typedef float f32x4 __attribute__((ext_vector_type(4)));
typedef __bf16 bf16x8 __attribute__((ext_vector_type(8)));
typedef __bf16 bf16x2 __attribute__((ext_vector_type(2)));
typedef unsigned short u16x8 __attribute__((ext_vector_type(8)));
typedef unsigned short u16x4 __attribute__((ext_vector_type(4)));

__device__ __forceinline__ unsigned short f2bf(float f) {
  union { float f; unsigned u; } v; v.f = f;
  unsigned u = v.u;
  return (unsigned short)((u + 0x7FFFu + ((u >> 16) & 1u)) >> 16);  // RNE
}
__device__ __forceinline__ float bf2f(unsigned short b) {
  union { unsigned u; float f; } v; v.u = ((unsigned)b) << 16;
  return v.f;
}
// packed f32x2 -> bf16x2 (single v_cvt_pk_bf16_f32 on gfx950)
__device__ __forceinline__ unsigned pk2bf(float a, float b) {
#if __has_builtin(__builtin_amdgcn_cvt_pk_bf16_f32)
  bf16x2 r = __builtin_amdgcn_cvt_pk_bf16_f32(a, b);
  return __builtin_bit_cast(unsigned, r);
#else
  return (unsigned)f2bf(a) | ((unsigned)f2bf(b) << 16);
#endif
}
__device__ __forceinline__ float fexp2(float x) {
#if __has_builtin(__builtin_amdgcn_exp2f)
  return __builtin_amdgcn_exp2f(x);  // raw v_exp_f32 (base-2)
#else
  return exp2f(x);
#endif
}
__device__ __forceinline__ f32x4 mfma16(u16x8 a, u16x8 b, f32x4 c) {
  return __builtin_amdgcn_mfma_f32_16x16x32_bf16(
      __builtin_bit_cast(bf16x8, a), __builtin_bit_cast(bf16x8, b), c, 0, 0, 0);
}
// async global->LDS, 16B per lane. LDS dest is wave-uniform base + lane*16.
__device__ __forceinline__ void gld16(const unsigned short* g, unsigned short* l) {
  __builtin_amdgcn_global_load_lds(
      (const __attribute__((address_space(1))) unsigned*)g,
      (__attribute__((address_space(3))) unsigned*)l, 16, 0, 0);
}

// ---------------------------------------------------------------- fp32 -> bf16
__global__ __launch_bounds__(256) void cvt_f32_bf16(const float* __restrict__ src,
                                                    unsigned short* __restrict__ dst,
                                                    int n) {
  int i = (blockIdx.x * 256 + threadIdx.x) * 8;
  if (i >= n) return;
  float4 a = *(const float4*)(src + i);
  float4 b = *(const float4*)(src + i + 4);
  uint4 r = {pk2bf(a.x, a.y), pk2bf(a.z, a.w), pk2bf(b.x, b.y), pk2bf(b.z, b.w)};
  *(uint4*)(dst + i) = r;
}

// ---------------------------------------------------- C[M,N] = A[M,K] @ Bt[N,K]^T
// 128x128 block tile, BK=128 (2 barriers per 128-deep K-chunk: half the drains
// of BK=64; no occupancy cost since grid <= 1.5 blocks/CU). Async
// global_load_lds 16B with XOR swizzle: LDS row r, slot s holds source chunk
// s^(r&15); fragment read slot = (ks*4+quad)^c. 4 waves 2x2, 64x64 each.
template <bool OUT_BF16>
__global__ __launch_bounds__(256) void gemm_bt_bf16(const unsigned short* __restrict__ A,
                                                    const unsigned short* __restrict__ Bt,
                                                    void* __restrict__ Cv,
                                                    int N, int K) {
  __shared__ alignas(16) unsigned short As[128 * 128];  // 32 KB
  __shared__ alignas(16) unsigned short Bs[128 * 128];  // 32 KB

  const int bn = blockIdx.x * 128, bm = blockIdx.y * 128;
  const int tid = threadIdx.x, w = tid >> 6, lane = tid & 63;
  const int c = lane & 15, quad = lane >> 4;
  const int wm = w >> 1, wn = w & 1;

  // staging: wave w owns rows [w*32, w*32+32) of both tiles.
  // gld16 covers 4 rows (64 lanes x 16B = 4 x 256B); lane -> row4 = lane>>4,
  // chunk = lane&15; source chunk = chunk ^ ((j*4 + row4)&15).
  const int r4 = lane >> 4, ch = lane & 15;
  const unsigned short* aRow = A + (size_t)(bm + w * 32 + r4) * K;
  const unsigned short* bRow = Bt + (size_t)(bn + w * 32 + r4) * K;
  unsigned short* AsW = As + (w * 32) * 128;
  unsigned short* BsW = Bs + (w * 32) * 128;

  f32x4 acc[4][4] = {};

  for (int k0 = 0; k0 < K; k0 += 128) {
#pragma unroll
    for (int j = 0; j < 8; j++) {
      const int sch = ch ^ ((j * 4 + r4) & 15);
      gld16(aRow + (size_t)(j * 4) * K + k0 + sch * 8, AsW + j * 4 * 128);
      gld16(bRow + (size_t)(j * 4) * K + k0 + sch * 8, BsW + j * 4 * 128);
    }
    __syncthreads();  // drain vmcnt -> tiles complete

#pragma unroll
    for (int ks = 0; ks < 4; ks++) {
      const int slot = (ks * 4 + quad) ^ c;
      u16x8 a[4], b[4];
#pragma unroll
      for (int mi = 0; mi < 4; mi++)
        a[mi] = *(const u16x8*)&As[(wm * 64 + mi * 16 + c) * 128 + slot * 8];
#pragma unroll
      for (int ni = 0; ni < 4; ni++)
        b[ni] = *(const u16x8*)&Bs[(wn * 64 + ni * 16 + c) * 128 + slot * 8];
#pragma unroll
      for (int mi = 0; mi < 4; mi++)
#pragma unroll
        for (int ni = 0; ni < 4; ni++)
          acc[mi][ni] = mfma16(a[mi], b[ni], acc[mi][ni]);
    }
    __syncthreads();  // protect LDS from next-iter overwrite
  }

#pragma unroll
  for (int mi = 0; mi < 4; mi++)
#pragma unroll
    for (int ni = 0; ni < 4; ni++)
#pragma unroll
      for (int r = 0; r < 4; r++) {
        size_t row = (size_t)(bm + wm * 64 + mi * 16 + quad * 4 + r);
        size_t col = (size_t)(bn + wn * 64 + ni * 16 + c);
        if (OUT_BF16)
          ((unsigned short*)Cv)[row * N + col] = f2bf(acc[mi][ni][r]);
        else
          ((float*)Cv)[row * N + col] = acc[mi][ni][r];
      }
}

// ------------------------------------------------------------------------ RoPE
// In-place on fused QKV buffer. Q pre-scaled by log2(e)/8 so attention scores
// are already in the exp2 domain (softmax base-2 == softmax base-e of s/8).
__global__ __launch_bounds__(256) void rope_kernel(unsigned short* __restrict__ QKV,
                                                   const float* __restrict__ cosb,
                                                   const float* __restrict__ sinb) {
  const int QP = T * HQ * (DH / 2);   // 2097152
  const int KP = T * HKV * (DH / 2);  // 524288
  int idx = blockIdx.x * 256 + threadIdx.x;
  if (idx >= QP + KP) return;
  unsigned short* p;
  int t, i;
  float sc;
  if (idx < QP) {
    t = idx / (HQ * DH / 2);
    int rem = idx - t * (HQ * DH / 2);
    i = rem & 31;
    p = QKV + (size_t)t * NQKV + rem * 2;
    sc = 0.125f * 1.44269504088896340736f;  // (1/sqrt(DH)) * log2(e)
  } else {
    int j = idx - QP;
    t = j / (HKV * DH / 2);
    int rem = j - t * (HKV * DH / 2);
    i = rem & 31;
    p = QKV + (size_t)t * NQKV + D + rem * 2;
    sc = 1.0f;
  }
  float x0 = bf2f(p[0]), x1 = bf2f(p[1]);
  float cs = cosb[t * 32 + i], sn = sinb[t * 32 + i];
  unsigned pk = pk2bf((x0 * cs - x1 * sn) * sc, (x0 * sn + x1 * cs) * sc);
  *(unsigned*)p = pk;  // p is pair-aligned (4B)
}

// ------------------------------------------------- V transpose: (T,dkv) -> (dkv,T)
// 64x64 LDS tile, coalesced both sides, pad 65 -> conflict-free.
__global__ __launch_bounds__(256) void transpose_v(const unsigned short* __restrict__ QKV,
                                                   unsigned short* __restrict__ VT) {
  __shared__ unsigned short Ts[64][65];
  const int tb = blockIdx.x, db = blockIdx.y;
  const int tid = threadIdx.x;
  const int r = tid >> 2, c0 = (tid & 3) * 16;
  const unsigned short* src = QKV + (size_t)(tb * 64 + r) * NQKV + (D + DKV) + db * 64 + c0;
  *(u16x8*)&Ts[r][c0]     = *(const u16x8*)src;
  *(u16x8*)&Ts[r][c0 + 8] = *(const u16x8*)(src + 8);
  __syncthreads();
  u16x8 a, b;
#pragma unroll
  for (int j = 0; j < 8; j++) a[j] = Ts[c0 + j][r];
#pragma unroll
  for (int j = 0; j < 8; j++) b[j] = Ts[c0 + 8 + j][r];
  unsigned short* dst = VT + (size_t)(db * 64 + r) * T + tb * 64 + c0;
  *(u16x8*)dst = a;
  *(u16x8*)(dst + 8) = b;
}

// ------------------------------------------------------------------- attention
// Flash-style, S^T formulation, GQA-grouped: block = (kv-head, 16-row q-tile),
// 4 waves = the 4 q-heads sharing this kv-head -> K/V staged ONCE per group.
// Each wave: 16 q-rows (one per lane-c, m/l/alpha are per-lane scalars).
// K and V^T tiles staged via global_load_lds with XOR swizzle.
// Scores arrive in exp2 domain (Q pre-scaled by log2e/8). LPT order.
__global__ __launch_bounds__(256) void attn_kernel(const unsigned short* __restrict__ QKV,
                                                   const unsigned short* __restrict__ VT,
                                                   unsigned short* __restrict__ Ob) {
  const int kh = blockIdx.x;                          // kv head 0..7
  const int qt = (int)(gridDim.y - 1 - blockIdx.y);   // LPT: long tiles first
  const int qbase = qt * 16;
  const int tid = threadIdx.x, w = tid >> 6, lane = tid & 63;
  const int c = lane & 15, quad = lane >> 4;
  const int h = kh * 4 + w;                           // this wave's q head

  __shared__ alignas(16) unsigned short Kt[64 * 64];      // (key, dh) swizzled, 8 KB
  __shared__ alignas(16) unsigned short Vt[64 * 64];      // (dh, key) swizzled, 8 KB
  __shared__ alignas(16) unsigned short Pb[4 * 16 * 72];  // per-wave P (q, key), 9 KB

  unsigned short* PbW = Pb + w * 16 * 72;

  // Q as B-fragments: q-row qbase+c, head h (pre-scaled by log2e/8 in rope)
  u16x8 qf[2];
  {
    const unsigned short* qp = QKV + (size_t)(qbase + c) * NQKV + h * DH + quad * 8;
    qf[0] = *(const u16x8*)qp;
    qf[1] = *(const u16x8*)(qp + 32);
  }

  // staging: wave w stages rows [w*16, w*16+16) of Kt and Vt; 2 gld16 each
  // (8 rows per call). lane -> row8 = lane>>3, chunk = lane&7,
  // swizzled source chunk = (lane&7)^(lane>>3).
  const int srow = lane >> 3;
  const int sch  = (lane & 7) ^ srow;
  const unsigned short* kgBase = QKV + D + (size_t)(w * 16 + srow) * NQKV + kh * DH + sch * 8;
  const unsigned short* vgBase = VT + (size_t)(kh * DH + w * 16 + srow) * T + sch * 8;
  unsigned short* KtW = Kt + (w * 16) * 64;
  unsigned short* VtW = Vt + (w * 16) * 64;

  f32x4 o[4] = {};
  float m = -INFINITY, l = 0.f;

  const int nFull = qt >> 2;  // diagonal key-tile index (keys qbase..qbase+15 live there)
  for (int st = 0; st <= nFull; st++) {
    __syncthreads();  // previous-iter reads done before overwrite
#pragma unroll
    for (int j = 0; j < 2; j++) {
      gld16(kgBase + ((size_t)st * 64 + (size_t)j * 8) * NQKV, KtW + j * 8 * 64);
      gld16(vgBase + (size_t)j * 8 * T + st * 64, VtW + j * 8 * 64);
    }
    __syncthreads();  // vmcnt drained -> tiles complete

    // S^T = K Q^T : A-frag = K rows, B-frag = Q. D[key=ni*16+quad*4+r][q=c].
    f32x4 sacc[4] = {};
#pragma unroll
    for (int ks = 0; ks < 2; ks++) {
#pragma unroll
      for (int ni = 0; ni < 4; ni++) {
        const int slot = (ks * 4 + quad) ^ (c & 7);
        u16x8 kf = *(const u16x8*)&Kt[(ni * 16 + c) * 64 + slot * 8];
        sacc[ni] = mfma16(kf, qf[ks], sacc[ni]);
      }
    }

    // causal mask: only diagonal tile (uniform branch)
    if (st == nFull) {
      const int qrow = qbase + c;
#pragma unroll
      for (int ni = 0; ni < 4; ni++)
#pragma unroll
        for (int r = 0; r < 4; r++) {
          int key = st * 64 + ni * 16 + quad * 4 + r;
          if (key > qrow) sacc[ni][r] = -INFINITY;
        }
    }

    // online softmax in exp2 domain; per-lane scalar m/l (q = c).
    float tmax = sacc[0][0];
#pragma unroll
    for (int ni = 0; ni < 4; ni++)
#pragma unroll
      for (int r = 0; r < 4; r++) tmax = fmaxf(tmax, sacc[ni][r]);
    tmax = fmaxf(tmax, __shfl_xor(tmax, 16, 64));
    tmax = fmaxf(tmax, __shfl_xor(tmax, 32, 64));
    float mnew = fmaxf(m, tmax);
    float alpha = fexp2(m - mnew);  // exp2(-inf)=0 on first tile
    m = mnew;

    float psum = 0.f;
#pragma unroll
    for (int ni = 0; ni < 4; ni++) {
      float p0 = fexp2(sacc[ni][0] - mnew);
      float p1 = fexp2(sacc[ni][1] - mnew);
      float p2 = fexp2(sacc[ni][2] - mnew);
      float p3 = fexp2(sacc[ni][3] - mnew);
      psum += (p0 + p1) + (p2 + p3);
      uint2 pr = {pk2bf(p0, p1), pk2bf(p2, p3)};
      // P^T (C-layout) -> P (q,key) rows: lane writes row c, cols ni*16+quad*4..+3
      *(uint2*)&PbW[c * 72 + ni * 16 + quad * 4] = pr;
    }
    psum += __shfl_xor(psum, 16, 64);
    psum += __shfl_xor(psum, 32, 64);
    l = l * alpha + psum;

    // broadcast alpha to O's C-layout rows (alpha uniform across quads per c)
    float aR[4];
#pragma unroll
    for (int r = 0; r < 4; r++) aR[r] = __shfl(alpha, quad * 4 + r, 64);
#pragma unroll
    for (int ni = 0; ni < 4; ni++)
#pragma unroll
      for (int r = 0; r < 4; r++) o[ni][r] *= aR[r];

    // O += P V : A-frag = P rows (own-wave LDS region), B-frag = V^T rows.
#pragma unroll
    for (int ks = 0; ks < 2; ks++) {
      u16x8 pf = *(const u16x8*)&PbW[c * 72 + ks * 32 + quad * 8];
#pragma unroll
      for (int ni = 0; ni < 4; ni++) {
        const int slot = (ks * 4 + quad) ^ (c & 7);
        u16x8 vf = *(const u16x8*)&Vt[(ni * 16 + c) * 64 + slot * 8];
        o[ni] = mfma16(pf, vf, o[ni]);
      }
    }
  }

  float lR[4];
#pragma unroll
  for (int r = 0; r < 4; r++) lR[r] = 1.0f / __shfl(l, quad * 4 + r, 64);
#pragma unroll
  for (int ni = 0; ni < 4; ni++)
#pragma unroll
    for (int r = 0; r < 4; r++) {
      size_t row = (size_t)(qbase + quad * 4 + r);
      size_t col = (size_t)(h * DH + ni * 16 + c);
      Ob[row * D + col] = f2bf(o[ni][r] * lR[r]);
    }
}

// ------------------------------------------------------------------- launcher
extern "C" void kernel_launch(void* const* d_in, const int* in_sizes, int n_in,
                              void* d_out, int out_size, void* d_ws, size_t ws_size,
                              hipStream_t stream) {
  const float* x  = (const float*)d_in[0];
  const float* Wq = (const float*)d_in[1];
  const float* Wk = (const float*)d_in[2];
  const float* Wv = (const float*)d_in[3];
  const float* Wo = (const float*)d_in[4];
  const float* rc = (const float*)d_in[5];
  const float* rs = (const float*)d_in[6];
  float* out = (float*)d_out;

  char* ws = (char*)d_ws;
  // bf16 workspace (bytes):
  //   xb    [0,8M)    x bf16; dead after QKV GEMM -> aliased by Ab
  //   wqkv  [8,20M)   fused QKV weights; dead after QKV GEMM -> VT reuses [8,10M)
  //   wob   [20,28M)
  //   qkvb  [28,40M)
  unsigned short* xb   = (unsigned short*)(ws);
  unsigned short* wqkv = (unsigned short*)(ws + (size_t)(8u  << 20));
  unsigned short* wob  = (unsigned short*)(ws + (size_t)(20u << 20));
  unsigned short* qkvb = (unsigned short*)(ws + (size_t)(28u << 20));
  unsigned short* Ab   = xb;                    // alias (x dead)
  unsigned short* VT   = wqkv;                  // alias (wqkv dead), 2 MB

  cvt_f32_bf16<<<dim3(T * D / 2048),   256, 0, stream>>>(x,  xb, T * D);
  cvt_f32_bf16<<<dim3(D * D / 2048),   256, 0, stream>>>(Wq, wqkv, D * D);
  cvt_f32_bf16<<<dim3(DKV * D / 2048), 256, 0, stream>>>(Wk, wqkv + (size_t)D * D, DKV * D);
  cvt_f32_bf16<<<dim3(DKV * D / 2048), 256, 0, stream>>>(Wv, wqkv + (size_t)(D + DKV) * D, DKV * D);
  cvt_f32_bf16<<<dim3(D * D / 2048),   256, 0, stream>>>(Wo, wob, D * D);

  // Fused QKV projection: (2048 x 3072) = x @ Wqkv^T
  gemm_bt_bf16<true><<<dim3(NQKV / 128, T / 128), 256, 0, stream>>>(xb, wqkv, qkvb, NQKV, D);

  {
    int pairs = T * HQ * (DH / 2) + T * HKV * (DH / 2);
    rope_kernel<<<dim3((pairs + 255) / 256), 256, 0, stream>>>(qkvb, rc, rs);
  }

  // V^T (512 x 2048) for attention B-fragments
  transpose_v<<<dim3(T / 64, DKV / 64), 256, 0, stream>>>(qkvb, VT);

  attn_kernel<<<dim3(HKV, T / 16), 256, 0, stream>>>(qkvb, VT, Ab);

  // Output projection: (2048 x 2048) = Ab @ Wo^T, fp32 out
  gemm_bt_bf16<false><<<dim3(D / 128, T / 128), 256, 0, stream>>>(Ab, wob, out, D, D);
}

// Round 5
// 233.389 us; speedup vs baseline: 2.7062x; 1.0442x over previous
//
#include <hip/hip_runtime.h>
#include <math.h>
#include <stdint.h>

// Problem constants (B=1)
static constexpr int T   = 2048;
static constexpr int D   = 2048;
static constexpr int HQ  = 32;
static constexpr int HKV = 8;
static constexpr int DH  = 64;
static constexpr int DKV = HKV * DH;       // 512
static constexpr int NQKV = D + 2 * DKV;   // 3072 fused QKV output width

typedef float f32x4 __attribute__((ext_vector_type(4)));
typedef __bf16 bf16x8 __attribute__((ext_vector_type(8)));
typedef __bf16 bf16x2 __attribute__((ext_vector_type(2)));
typedef unsigned short u16x8 __attribute__((ext_vector_type(8)));
typedef unsigned short u16x4 __attribute__((ext_vector_type(4)));

__device__ __forceinline__ unsigned short f2bf(float f) {
  union { float f; unsigned u; } v; v.f = f;
  unsigned u = v.u;
  return (unsigned short)((u + 0x7FFFu + ((u >> 16) & 1u)) >> 16);  // RNE
}
__device__ __forceinline__ float bf2f(unsigned short b) {
  union { unsigned u; float f; } v; v.u = ((unsigned)b) << 16;
  return v.f;
}
// packed f32x2 -> bf16x2 (single v_cvt_pk_bf16_f32 on gfx950)
__device__ __forceinline__ unsigned pk2bf(float a, float b) {
#if __has_builtin(__builtin_amdgcn_cvt_pk_bf16_f32)
  bf16x2 r = __builtin_amdgcn_cvt_pk_bf16_f32(a, b);
  return __builtin_bit_cast(unsigned, r);
#else
  return (unsigned)f2bf(a) | ((unsigned)f2bf(b) << 16);
#endif
}
__device__ __forceinline__ float fexp2(float x) {
#if __has_builtin(__builtin_amdgcn_exp2f)
  return __builtin_amdgcn_exp2f(x);  // raw v_exp_f32 (base-2)
#else
  return exp2f(x);
#endif
}
__device__ __forceinline__ float frcp(float x) {
#if __has_builtin(__builtin_amdgcn_rcpf)
  return __builtin_amdgcn_rcpf(x);   // v_rcp_f32, ~1ulp — fine for bf16 output
#else
  return 1.0f / x;
#endif
}
__device__ __forceinline__ f32x4 mfma16(u16x8 a, u16x8 b, f32x4 c) {
  return __builtin_amdgcn_mfma_f32_16x16x32_bf16(
      __builtin_bit_cast(bf16x8, a), __builtin_bit_cast(bf16x8, b), c, 0, 0, 0);
}
// async global->LDS, 16B per lane. LDS dest is wave-uniform base + lane*16.
__device__ __forceinline__ void gld16(const unsigned short* g, unsigned short* l) {
  __builtin_amdgcn_global_load_lds(
      (const __attribute__((address_space(1))) unsigned*)g,
      (__attribute__((address_space(3))) unsigned*)l, 16, 0, 0);
}

// --------------------------------------------- fused fp32 -> bf16 for all inputs
// One launch converts x, Wq, Wk, Wv, Wo. Segments in units of 2048-element
// blocks (256 thr x 8): x 2048 | Wq 2048 | Wk 512 | Wv 512 | Wo 2048 = 7168.
__global__ __launch_bounds__(256) void cvt_all(const float* __restrict__ x,
                                               const float* __restrict__ Wq,
                                               const float* __restrict__ Wk,
                                               const float* __restrict__ Wv,
                                               const float* __restrict__ Wo,
                                               unsigned short* __restrict__ xb,
                                               unsigned short* __restrict__ wqkv,
                                               unsigned short* __restrict__ wob) {
  int b = blockIdx.x;
  const float* src;
  unsigned short* dst;
  if (b < 2048)      { src = x;  dst = xb; }
  else if (b < 4096) { src = Wq; dst = wqkv;                          b -= 2048; }
  else if (b < 4608) { src = Wk; dst = wqkv + (size_t)D * D;          b -= 4096; }
  else if (b < 5120) { src = Wv; dst = wqkv + (size_t)(D + DKV) * D;  b -= 4608; }
  else               { src = Wo; dst = wob;                           b -= 5120; }
  size_t i = ((size_t)b * 256 + threadIdx.x) * 8;
  float4 a = *(const float4*)(src + i);
  float4 c = *(const float4*)(src + i + 4);
  uint4 r = {pk2bf(a.x, a.y), pk2bf(a.z, a.w), pk2bf(c.x, c.y), pk2bf(c.z, c.w)};
  *(uint4*)(dst + i) = r;
}

// ---------------------------------------------------- C[M,N] = A[M,K] @ Bt[N,K]^T
// 128x128 block tile, BK=128. Async global_load_lds 16B with XOR swizzle:
// LDS row r, slot s holds source chunk s^(r&15); fragment read slot =
// (ks*4+quad)^c. 4 waves 2x2, 64x64 each.
template <bool OUT_BF16>
__global__ __launch_bounds__(256) void gemm_bt_bf16(const unsigned short* __restrict__ A,
                                                    const unsigned short* __restrict__ Bt,
                                                    void* __restrict__ Cv,
                                                    int N, int K) {
  __shared__ alignas(16) unsigned short As[128 * 128];  // 32 KB
  __shared__ alignas(16) unsigned short Bs[128 * 128];  // 32 KB

  const int bn = blockIdx.x * 128, bm = blockIdx.y * 128;
  const int tid = threadIdx.x, w = tid >> 6, lane = tid & 63;
  const int c = lane & 15, quad = lane >> 4;
  const int wm = w >> 1, wn = w & 1;

  const int r4 = lane >> 4, ch = lane & 15;
  const unsigned short* aRow = A + (size_t)(bm + w * 32 + r4) * K;
  const unsigned short* bRow = Bt + (size_t)(bn + w * 32 + r4) * K;
  unsigned short* AsW = As + (w * 32) * 128;
  unsigned short* BsW = Bs + (w * 32) * 128;

  f32x4 acc[4][4] = {};

  for (int k0 = 0; k0 < K; k0 += 128) {
#pragma unroll
    for (int j = 0; j < 8; j++) {
      const int sch = ch ^ ((j * 4 + r4) & 15);
      gld16(aRow + (size_t)(j * 4) * K + k0 + sch * 8, AsW + j * 4 * 128);
      gld16(bRow + (size_t)(j * 4) * K + k0 + sch * 8, BsW + j * 4 * 128);
    }
    __syncthreads();  // drain vmcnt -> tiles complete

#pragma unroll
    for (int ks = 0; ks < 4; ks++) {
      const int slot = (ks * 4 + quad) ^ c;
      u16x8 a[4], b[4];
#pragma unroll
      for (int mi = 0; mi < 4; mi++)
        a[mi] = *(const u16x8*)&As[(wm * 64 + mi * 16 + c) * 128 + slot * 8];
#pragma unroll
      for (int ni = 0; ni < 4; ni++)
        b[ni] = *(const u16x8*)&Bs[(wn * 64 + ni * 16 + c) * 128 + slot * 8];
#pragma unroll
      for (int mi = 0; mi < 4; mi++)
#pragma unroll
        for (int ni = 0; ni < 4; ni++)
          acc[mi][ni] = mfma16(a[mi], b[ni], acc[mi][ni]);
    }
    __syncthreads();  // protect LDS from next-iter overwrite
  }

#pragma unroll
  for (int mi = 0; mi < 4; mi++)
#pragma unroll
    for (int ni = 0; ni < 4; ni++)
#pragma unroll
      for (int r = 0; r < 4; r++) {
        size_t row = (size_t)(bm + wm * 64 + mi * 16 + quad * 4 + r);
        size_t col = (size_t)(bn + wn * 64 + ni * 16 + c);
        if (OUT_BF16)
          ((unsigned short*)Cv)[row * N + col] = f2bf(acc[mi][ni][r]);
        else
          ((float*)Cv)[row * N + col] = acc[mi][ni][r];
      }
}

// ----------------------------------------- fused RoPE (Q,K) + V transpose
// Blocks [0, 10240): rope in-place on qkvb; Q pre-scaled by log2(e)/8 so
// attention scores are in the exp2 domain. Blocks [10240, 10496): 64x64
// transpose of V (T,dkv)->(dkv,T), pad-65 LDS, conflict-free. V is untouched
// by rope so the two jobs are independent.
__global__ __launch_bounds__(256) void rope_tv(unsigned short* __restrict__ QKV,
                                               const float* __restrict__ cosb,
                                               const float* __restrict__ sinb,
                                               unsigned short* __restrict__ VT) {
  const int QP = T * HQ * (DH / 2);   // 2097152
  const int KP = T * HKV * (DH / 2);  // 524288  -> (QP+KP)/256 = 10240 blocks
  if (blockIdx.x < 10240) {
    int idx = blockIdx.x * 256 + threadIdx.x;
    unsigned short* p;
    int t, i;
    float sc;
    if (idx < QP) {
      t = idx / (HQ * DH / 2);
      int rem = idx - t * (HQ * DH / 2);
      i = rem & 31;
      p = QKV + (size_t)t * NQKV + rem * 2;
      sc = 0.125f * 1.44269504088896340736f;  // (1/sqrt(DH)) * log2(e)
    } else {
      int j = idx - QP;
      t = j / (HKV * DH / 2);
      int rem = j - t * (HKV * DH / 2);
      i = rem & 31;
      p = QKV + (size_t)t * NQKV + D + rem * 2;
      sc = 1.0f;
    }
    float x0 = bf2f(p[0]), x1 = bf2f(p[1]);
    float cs = cosb[t * 32 + i], sn = sinb[t * 32 + i];
    *(unsigned*)p = pk2bf((x0 * cs - x1 * sn) * sc, (x0 * sn + x1 * cs) * sc);
  } else {
    __shared__ unsigned short Ts[64][65];
    const int bid = blockIdx.x - 10240;
    const int tb = bid & 31, db = bid >> 5;   // tb: T/64, db: DKV/64
    const int tid = threadIdx.x;
    const int r = tid >> 2, c0 = (tid & 3) * 16;
    const unsigned short* src = QKV + (size_t)(tb * 64 + r) * NQKV + (D + DKV) + db * 64 + c0;
    *(u16x8*)&Ts[r][c0]     = *(const u16x8*)src;
    *(u16x8*)&Ts[r][c0 + 8] = *(const u16x8*)(src + 8);
    __syncthreads();
    u16x8 a, b;
#pragma unroll
    for (int j = 0; j < 8; j++) a[j] = Ts[c0 + j][r];
#pragma unroll
    for (int j = 0; j < 8; j++) b[j] = Ts[c0 + 8 + j][r];
    unsigned short* dst = VT + (size_t)(db * 64 + r) * T + tb * 64 + c0;
    *(u16x8*)dst = a;
    *(u16x8*)(dst + 8) = b;
  }
}

// ------------------------------------------------------------------- attention
// Flash-style, S^T formulation, GQA-grouped: block = (kv-head, 16-row q-tile),
// 4 waves = the 4 q-heads sharing this kv-head -> K/V staged ONCE per group.
// Each wave: 16 q-rows (one per lane-c, m/l/alpha are per-lane scalars).
// K and V^T tiles staged via global_load_lds with XOR swizzle.
// Scores arrive in exp2 domain (Q pre-scaled by log2e/8). LPT order.
__global__ __launch_bounds__(256) void attn_kernel(const unsigned short* __restrict__ QKV,
                                                   const unsigned short* __restrict__ VT,
                                                   unsigned short* __restrict__ Ob) {
  const int kh = blockIdx.x;                          // kv head 0..7
  const int qt = (int)(gridDim.y - 1 - blockIdx.y);   // LPT: long tiles first
  const int qbase = qt * 16;
  const int tid = threadIdx.x, w = tid >> 6, lane = tid & 63;
  const int c = lane & 15, quad = lane >> 4;
  const int h = kh * 4 + w;                           // this wave's q head

  __shared__ alignas(16) unsigned short Kt[64 * 64];      // (key, dh) swizzled, 8 KB
  __shared__ alignas(16) unsigned short Vt[64 * 64];      // (dh, key) swizzled, 8 KB
  __shared__ alignas(16) unsigned short Pb[4 * 16 * 72];  // per-wave P (q, key), 9 KB

  unsigned short* PbW = Pb + w * 16 * 72;

  // Q as B-fragments: q-row qbase+c, head h (pre-scaled by log2e/8 in rope)
  u16x8 qf[2];
  {
    const unsigned short* qp = QKV + (size_t)(qbase + c) * NQKV + h * DH + quad * 8;
    qf[0] = *(const u16x8*)qp;
    qf[1] = *(const u16x8*)(qp + 32);
  }

  // staging: wave w stages rows [w*16, w*16+16) of Kt and Vt; 2 gld16 each.
  const int srow = lane >> 3;
  const int sch  = (lane & 7) ^ srow;
  const unsigned short* kgBase = QKV + D + (size_t)(w * 16 + srow) * NQKV + kh * DH + sch * 8;
  const unsigned short* vgBase = VT + (size_t)(kh * DH + w * 16 + srow) * T + sch * 8;
  unsigned short* KtW = Kt + (w * 16) * 64;
  unsigned short* VtW = Vt + (w * 16) * 64;

  f32x4 o[4] = {};
  float m = -INFINITY, l = 0.f;

  const int nFull = qt >> 2;  // diagonal key-tile index
  for (int st = 0; st <= nFull; st++) {
    __syncthreads();  // previous-iter reads done before overwrite
#pragma unroll
    for (int j = 0; j < 2; j++) {
      gld16(kgBase + ((size_t)st * 64 + (size_t)j * 8) * NQKV, KtW + j * 8 * 64);
      gld16(vgBase + (size_t)j * 8 * T + st * 64, VtW + j * 8 * 64);
    }
    __syncthreads();  // vmcnt drained -> tiles complete

    // S^T = K Q^T : A-frag = K rows, B-frag = Q. D[key=ni*16+quad*4+r][q=c].
    f32x4 sacc[4] = {};
#pragma unroll
    for (int ks = 0; ks < 2; ks++) {
#pragma unroll
      for (int ni = 0; ni < 4; ni++) {
        const int slot = (ks * 4 + quad) ^ (c & 7);
        u16x8 kf = *(const u16x8*)&Kt[(ni * 16 + c) * 64 + slot * 8];
        sacc[ni] = mfma16(kf, qf[ks], sacc[ni]);
      }
    }

    // causal mask: only diagonal tile (uniform branch)
    if (st == nFull) {
      const int qrow = qbase + c;
#pragma unroll
      for (int ni = 0; ni < 4; ni++)
#pragma unroll
        for (int r = 0; r < 4; r++) {
          int key = st * 64 + ni * 16 + quad * 4 + r;
          if (key > qrow) sacc[ni][r] = -INFINITY;
        }
    }

    // online softmax in exp2 domain; per-lane scalar m/l (q = c).
    float tmax = sacc[0][0];
#pragma unroll
    for (int ni = 0; ni < 4; ni++)
#pragma unroll
      for (int r = 0; r < 4; r++) tmax = fmaxf(tmax, sacc[ni][r]);
    tmax = fmaxf(tmax, __shfl_xor(tmax, 16, 64));
    tmax = fmaxf(tmax, __shfl_xor(tmax, 32, 64));
    float mnew = fmaxf(m, tmax);
    float alpha = fexp2(m - mnew);  // exp2(-inf)=0 on first tile
    m = mnew;

    float psum = 0.f;
#pragma unroll
    for (int ni = 0; ni < 4; ni++) {
      float p0 = fexp2(sacc[ni][0] - mnew);
      float p1 = fexp2(sacc[ni][1] - mnew);
      float p2 = fexp2(sacc[ni][2] - mnew);
      float p3 = fexp2(sacc[ni][3] - mnew);
      psum += (p0 + p1) + (p2 + p3);
      uint2 pr = {pk2bf(p0, p1), pk2bf(p2, p3)};
      *(uint2*)&PbW[c * 72 + ni * 16 + quad * 4] = pr;
    }
    psum += __shfl_xor(psum, 16, 64);
    psum += __shfl_xor(psum, 32, 64);
    l = l * alpha + psum;

    // broadcast alpha to O's C-layout rows (alpha uniform across quads per c)
    float aR[4];
#pragma unroll
    for (int r = 0; r < 4; r++) aR[r] = __shfl(alpha, quad * 4 + r, 64);
#pragma unroll
    for (int ni = 0; ni < 4; ni++)
#pragma unroll
      for (int r = 0; r < 4; r++) o[ni][r] *= aR[r];

    // O += P V : A-frag = P rows (own-wave LDS region), B-frag = V^T rows.
#pragma unroll
    for (int ks = 0; ks < 2; ks++) {
      u16x8 pf = *(const u16x8*)&PbW[c * 72 + ks * 32 + quad * 8];
#pragma unroll
      for (int ni = 0; ni < 4; ni++) {
        const int slot = (ks * 4 + quad) ^ (c & 7);
        u16x8 vf = *(const u16x8*)&Vt[(ni * 16 + c) * 64 + slot * 8];
        o[ni] = mfma16(pf, vf, o[ni]);
      }
    }
  }

  float lR[4];
#pragma unroll
  for (int r = 0; r < 4; r++) lR[r] = frcp(__shfl(l, quad * 4 + r, 64));
#pragma unroll
  for (int ni = 0; ni < 4; ni++)
#pragma unroll
    for (int r = 0; r < 4; r++) {
      size_t row = (size_t)(qbase + quad * 4 + r);
      size_t col = (size_t)(h * DH + ni * 16 + c);
      Ob[row * D + col] = f2bf(o[ni][r] * lR[r]);
    }
}

// ------------------------------------------------------------------- launcher
extern "C" void kernel_launch(void* const* d_in, const int* in_sizes, int n_in,
                              void* d_out, int out_size, void* d_ws, size_t ws_size,
                              hipStream_t stream) {
  const float* x  = (const float*)d_in[0];
  const float* Wq = (const float*)d_in[1];
  const float* Wk = (const float*)d_in[2];
  const float* Wv = (const float*)d_in[3];
  const float* Wo = (const float*)d_in[4];
  const float* rc = (const float*)d_in[5];
  const float* rs = (const float*)d_in[6];
  float* out = (float*)d_out;

  char* ws = (char*)d_ws;
  // bf16 workspace (bytes):
  //   xb    [0,8M)    x bf16; dead after QKV GEMM -> aliased by Ab
  //   wqkv  [8,20M)   fused QKV weights; dead after QKV GEMM -> VT reuses [8,10M)
  //   wob   [20,28M)
  //   qkvb  [28,40M)
  unsigned short* xb   = (unsigned short*)(ws);
  unsigned short* wqkv = (unsigned short*)(ws + (size_t)(8u  << 20));
  unsigned short* wob  = (unsigned short*)(ws + (size_t)(20u << 20));
  unsigned short* qkvb = (unsigned short*)(ws + (size_t)(28u << 20));
  unsigned short* Ab   = xb;                    // alias (x dead)
  unsigned short* VT   = wqkv;                  // alias (wqkv dead), 2 MB

  // 1) all fp32->bf16 conversions in one launch
  cvt_all<<<dim3(7168), 256, 0, stream>>>(x, Wq, Wk, Wv, Wo, xb, wqkv, wob);

  // 2) fused QKV projection: (2048 x 3072) = x @ Wqkv^T
  gemm_bt_bf16<true><<<dim3(NQKV / 128, T / 128), 256, 0, stream>>>(xb, wqkv, qkvb, NQKV, D);

  // 3) RoPE on Q,K (+exp2-domain Q scale) and V^T, one launch
  rope_tv<<<dim3(10240 + 256), 256, 0, stream>>>(qkvb, rc, rs, VT);

  // 4) attention
  attn_kernel<<<dim3(HKV, T / 16), 256, 0, stream>>>(qkvb, VT, Ab);

  // 5) output projection: (2048 x 2048) = Ab @ Wo^T, fp32 out
  gemm_bt_bf16<false><<<dim3(D / 128, T / 128), 256, 0, stream>>>(Ab, wob, out, D, D);
}

// Round 6
// 228.306 us; speedup vs baseline: 2.7664x; 1.0223x over previous
//
#include <hip/hip_runtime.h>
#include <math.h>
#include <stdint.h>

// Problem constants (B=1)
static constexpr int T   = 2048;
static constexpr int D   = 2048;
static constexpr int HQ  = 32;
static constexpr int HKV = 8;
static constexpr int DH  = 64;
static constexpr int DKV = HKV * DH;       // 512
static constexpr int NQKV = D + 2 * DKV;   // 3072 fused QKV output width

typedef float f32x4 __attribute__((ext_vector_type(4)));
typedef __bf16 bf16x8 __attribute__((ext_vector_type(8)));
typedef __bf16 bf16x2 __attribute__((ext_vector_type(2)));
typedef unsigned short u16x8 __attribute__((ext_vector_type(8)));
typedef unsigned short u16x4 __attribute__((ext_vector_type(4)));

__device__ __forceinline__ unsigned short f2bf(float f) {
  union { float f; unsigned u; } v; v.f = f;
  unsigned u = v.u;
  return (unsigned short)((u + 0x7FFFu + ((u >> 16) & 1u)) >> 16);  // RNE
}
__device__ __forceinline__ float bf2f(unsigned short b) {
  union { unsigned u; float f; } v; v.u = ((unsigned)b) << 16;
  return v.f;
}
// packed f32x2 -> bf16x2 (single v_cvt_pk_bf16_f32 on gfx950)
__device__ __forceinline__ unsigned pk2bf(float a, float b) {
#if __has_builtin(__builtin_amdgcn_cvt_pk_bf16_f32)
  bf16x2 r = __builtin_amdgcn_cvt_pk_bf16_f32(a, b);
  return __builtin_bit_cast(unsigned, r);
#else
  return (unsigned)f2bf(a) | ((unsigned)f2bf(b) << 16);
#endif
}
__device__ __forceinline__ float fexp2(float x) {
#if __has_builtin(__builtin_amdgcn_exp2f)
  return __builtin_amdgcn_exp2f(x);  // raw v_exp_f32 (base-2)
#else
  return exp2f(x);
#endif
}
__device__ __forceinline__ float frcp(float x) {
#if __has_builtin(__builtin_amdgcn_rcpf)
  return __builtin_amdgcn_rcpf(x);   // v_rcp_f32, ~1ulp — fine for bf16 output
#else
  return 1.0f / x;
#endif
}
__device__ __forceinline__ f32x4 mfma16(u16x8 a, u16x8 b, f32x4 c) {
  return __builtin_amdgcn_mfma_f32_16x16x32_bf16(
      __builtin_bit_cast(bf16x8, a), __builtin_bit_cast(bf16x8, b), c, 0, 0, 0);
}
// async global->LDS, 16B per lane. LDS dest is wave-uniform base + lane*16.
__device__ __forceinline__ void gld16(const unsigned short* g, unsigned short* l) {
  __builtin_amdgcn_global_load_lds(
      (const __attribute__((address_space(1))) unsigned*)g,
      (__attribute__((address_space(3))) unsigned*)l, 16, 0, 0);
}

// --------------------------------------------- fused fp32 -> bf16 for all inputs
// One launch converts x, Wq, Wk, Wv, Wo. Segments in units of 2048-element
// blocks (256 thr x 8): x 2048 | Wq 2048 | Wk 512 | Wv 512 | Wo 2048 = 7168.
__global__ __launch_bounds__(256) void cvt_all(const float* __restrict__ x,
                                               const float* __restrict__ Wq,
                                               const float* __restrict__ Wk,
                                               const float* __restrict__ Wv,
                                               const float* __restrict__ Wo,
                                               unsigned short* __restrict__ xb,
                                               unsigned short* __restrict__ wqkv,
                                               unsigned short* __restrict__ wob) {
  int b = blockIdx.x;
  const float* src;
  unsigned short* dst;
  if (b < 2048)      { src = x;  dst = xb; }
  else if (b < 4096) { src = Wq; dst = wqkv;                          b -= 2048; }
  else if (b < 4608) { src = Wk; dst = wqkv + (size_t)D * D;          b -= 4096; }
  else if (b < 5120) { src = Wv; dst = wqkv + (size_t)(D + DKV) * D;  b -= 4608; }
  else               { src = Wo; dst = wob;                           b -= 5120; }
  size_t i = ((size_t)b * 256 + threadIdx.x) * 8;
  float4 a = *(const float4*)(src + i);
  float4 c = *(const float4*)(src + i + 4);
  uint4 r = {pk2bf(a.x, a.y), pk2bf(a.z, a.w), pk2bf(c.x, c.y), pk2bf(c.z, c.w)};
  *(uint4*)(dst + i) = r;
}

// ---------------------------------------------------- C[M,N] = A[M,K] @ Bt[N,K]^T
// 64M x 128N block tile, BK=128. LDS 48 KB -> exactly 3 blocks/CU resident, so
// co-resident blocks hide each other's barrier drains (m114 overlap). Async
// global_load_lds 16B with XOR swizzle: LDS row r, slot s holds source chunk
// s ^ (r&15); fragment read slot = (ks*4+quad) ^ c. 4 waves side-by-side in N;
// each wave computes 64M x 32N via acc[4][2].
template <bool OUT_BF16>
__global__ __launch_bounds__(256) void gemm_bt_bf16(const unsigned short* __restrict__ A,
                                                    const unsigned short* __restrict__ Bt,
                                                    void* __restrict__ Cv,
                                                    int N, int K) {
  __shared__ alignas(16) unsigned short As[64 * 128];   // 16 KB
  __shared__ alignas(16) unsigned short Bs[128 * 128];  // 32 KB

  const int bn = blockIdx.x * 128, bm = blockIdx.y * 64;
  const int tid = threadIdx.x, w = tid >> 6, lane = tid & 63;
  const int c = lane & 15, quad = lane >> 4;

  // staging: wave w owns A rows [w*16, w*16+16) and B rows [w*32, w*32+32).
  // Each gld16 covers 4 rows (64 lanes x 16B); lane -> row4 = lane>>4,
  // chunk = lane&15; source chunk = chunk ^ (row&15).
  const int r4 = lane >> 4, ch = lane & 15;
  const unsigned short* aRow = A + (size_t)(bm + w * 16 + r4) * K;
  const unsigned short* bRow = Bt + (size_t)(bn + w * 32 + r4) * K;
  unsigned short* AsW = As + (w * 16) * 128;
  unsigned short* BsW = Bs + (w * 32) * 128;

  f32x4 acc[4][2] = {};

  for (int k0 = 0; k0 < K; k0 += 128) {
#pragma unroll
    for (int j = 0; j < 4; j++) {
      const int sch = ch ^ ((j * 4 + r4) & 15);
      gld16(aRow + (size_t)(j * 4) * K + k0 + sch * 8, AsW + j * 4 * 128);
    }
#pragma unroll
    for (int j = 0; j < 8; j++) {
      const int sch = ch ^ ((j * 4 + r4) & 15);
      gld16(bRow + (size_t)(j * 4) * K + k0 + sch * 8, BsW + j * 4 * 128);
    }
    __syncthreads();  // drain vmcnt -> tiles complete

#pragma unroll
    for (int ks = 0; ks < 4; ks++) {
      const int slot = (ks * 4 + quad) ^ c;
      u16x8 a[4], b[2];
#pragma unroll
      for (int mi = 0; mi < 4; mi++)
        a[mi] = *(const u16x8*)&As[(mi * 16 + c) * 128 + slot * 8];
#pragma unroll
      for (int ni = 0; ni < 2; ni++)
        b[ni] = *(const u16x8*)&Bs[(w * 32 + ni * 16 + c) * 128 + slot * 8];
#pragma unroll
      for (int mi = 0; mi < 4; mi++)
#pragma unroll
        for (int ni = 0; ni < 2; ni++)
          acc[mi][ni] = mfma16(a[mi], b[ni], acc[mi][ni]);
    }
    __syncthreads();  // protect LDS from next-iter overwrite
  }

#pragma unroll
  for (int mi = 0; mi < 4; mi++)
#pragma unroll
    for (int ni = 0; ni < 2; ni++)
#pragma unroll
      for (int r = 0; r < 4; r++) {
        size_t row = (size_t)(bm + mi * 16 + quad * 4 + r);
        size_t col = (size_t)(bn + w * 32 + ni * 16 + c);
        if (OUT_BF16)
          ((unsigned short*)Cv)[row * N + col] = f2bf(acc[mi][ni][r]);
        else
          ((float*)Cv)[row * N + col] = acc[mi][ni][r];
      }
}

// ----------------------------------------- fused RoPE (Q,K) + V transpose
// Blocks [0, 10240): rope in-place on qkvb; Q pre-scaled by log2(e)/8 so
// attention scores are in the exp2 domain. Blocks [10240, 10496): 64x64
// transpose of V (T,dkv)->(dkv,T), pad-65 LDS, conflict-free.
__global__ __launch_bounds__(256) void rope_tv(unsigned short* __restrict__ QKV,
                                               const float* __restrict__ cosb,
                                               const float* __restrict__ sinb,
                                               unsigned short* __restrict__ VT) {
  const int QP = T * HQ * (DH / 2);   // 2097152
  if (blockIdx.x < 10240) {
    int idx = blockIdx.x * 256 + threadIdx.x;
    unsigned short* p;
    int t, i;
    float sc;
    if (idx < QP) {
      t = idx / (HQ * DH / 2);
      int rem = idx - t * (HQ * DH / 2);
      i = rem & 31;
      p = QKV + (size_t)t * NQKV + rem * 2;
      sc = 0.125f * 1.44269504088896340736f;  // (1/sqrt(DH)) * log2(e)
    } else {
      int j = idx - QP;
      t = j / (HKV * DH / 2);
      int rem = j - t * (HKV * DH / 2);
      i = rem & 31;
      p = QKV + (size_t)t * NQKV + D + rem * 2;
      sc = 1.0f;
    }
    float x0 = bf2f(p[0]), x1 = bf2f(p[1]);
    float cs = cosb[t * 32 + i], sn = sinb[t * 32 + i];
    *(unsigned*)p = pk2bf((x0 * cs - x1 * sn) * sc, (x0 * sn + x1 * cs) * sc);
  } else {
    __shared__ unsigned short Ts[64][65];
    const int bid = blockIdx.x - 10240;
    const int tb = bid & 31, db = bid >> 5;   // tb: T/64, db: DKV/64
    const int tid = threadIdx.x;
    const int r = tid >> 2, c0 = (tid & 3) * 16;
    const unsigned short* src = QKV + (size_t)(tb * 64 + r) * NQKV + (D + DKV) + db * 64 + c0;
    *(u16x8*)&Ts[r][c0]     = *(const u16x8*)src;
    *(u16x8*)&Ts[r][c0 + 8] = *(const u16x8*)(src + 8);
    __syncthreads();
    u16x8 a, b;
#pragma unroll
    for (int j = 0; j < 8; j++) a[j] = Ts[c0 + j][r];
#pragma unroll
    for (int j = 0; j < 8; j++) b[j] = Ts[c0 + 8 + j][r];
    unsigned short* dst = VT + (size_t)(db * 64 + r) * T + tb * 64 + c0;
    *(u16x8*)dst = a;
    *(u16x8*)(dst + 8) = b;
  }
}

// ------------------------------------------------------------------- attention
// Flash-style, S^T formulation, GQA-grouped: block = (kv-head, balanced pair of
// 16-row q-tiles {by, 127-by}), so every block runs 32-34 tile-iterations (no
// drain tail; grid 8x64 = 512 = 2.0 blocks/CU). 4 waves = the 4 q-heads
// sharing one kv-head -> K/V staged once per group. One q-row per lane-c:
// m/l/alpha are per-lane scalars. Scores in exp2 domain (Q pre-scaled).
__global__ __launch_bounds__(256) void attn_kernel(const unsigned short* __restrict__ QKV,
                                                   const unsigned short* __restrict__ VT,
                                                   unsigned short* __restrict__ Ob) {
  const int kh = blockIdx.x;                 // kv head 0..7
  const int NQT = T / 16;                    // 128 q-tiles
  const int tid = threadIdx.x, w = tid >> 6, lane = tid & 63;
  const int c = lane & 15, quad = lane >> 4;
  const int h = kh * 4 + w;                  // this wave's q head

  __shared__ alignas(16) unsigned short Kt[64 * 64];      // (key, dh) swizzled, 8 KB
  __shared__ alignas(16) unsigned short Vt[64 * 64];      // (dh, key) swizzled, 8 KB
  __shared__ alignas(16) unsigned short Pb[4 * 16 * 72];  // per-wave P (q, key), 9 KB

  unsigned short* PbW = Pb + w * 16 * 72;

  // staging: wave w stages rows [w*16, w*16+16) of Kt and Vt; 2 gld16 each.
  const int srow = lane >> 3;
  const int sch  = (lane & 7) ^ srow;
  const unsigned short* kgBase = QKV + D + (size_t)(w * 16 + srow) * NQKV + kh * DH + sch * 8;
  const unsigned short* vgBase = VT + (size_t)(kh * DH + w * 16 + srow) * T + sch * 8;
  unsigned short* KtW = Kt + (w * 16) * 64;
  unsigned short* VtW = Vt + (w * 16) * 64;

#pragma unroll 1
  for (int pass = 0; pass < 2; pass++) {
    const int qt = pass ? (NQT - 1 - (int)blockIdx.y) : (int)blockIdx.y;
    const int qbase = qt * 16;

    // Q as B-fragments: q-row qbase+c, head h (pre-scaled by log2e/8 in rope)
    u16x8 qf[2];
    {
      const unsigned short* qp = QKV + (size_t)(qbase + c) * NQKV + h * DH + quad * 8;
      qf[0] = *(const u16x8*)qp;
      qf[1] = *(const u16x8*)(qp + 32);
    }

    f32x4 o[4] = {};
    float m = -INFINITY, l = 0.f;

    const int nFull = qt >> 2;  // diagonal key-tile index
    for (int st = 0; st <= nFull; st++) {
      __syncthreads();  // previous-iter reads done before overwrite
#pragma unroll
      for (int j = 0; j < 2; j++) {
        gld16(kgBase + ((size_t)st * 64 + (size_t)j * 8) * NQKV, KtW + j * 8 * 64);
        gld16(vgBase + (size_t)j * 8 * T + st * 64, VtW + j * 8 * 64);
      }
      __syncthreads();  // vmcnt drained -> tiles complete

      // S^T = K Q^T : A-frag = K rows, B-frag = Q. D[key=ni*16+quad*4+r][q=c].
      f32x4 sacc[4] = {};
#pragma unroll
      for (int ks = 0; ks < 2; ks++) {
#pragma unroll
        for (int ni = 0; ni < 4; ni++) {
          const int slot = (ks * 4 + quad) ^ (c & 7);
          u16x8 kf = *(const u16x8*)&Kt[(ni * 16 + c) * 64 + slot * 8];
          sacc[ni] = mfma16(kf, qf[ks], sacc[ni]);
        }
      }

      // causal mask: only diagonal tile (uniform branch)
      if (st == nFull) {
        const int qrow = qbase + c;
#pragma unroll
        for (int ni = 0; ni < 4; ni++)
#pragma unroll
          for (int r = 0; r < 4; r++) {
            int key = st * 64 + ni * 16 + quad * 4 + r;
            if (key > qrow) sacc[ni][r] = -INFINITY;
          }
      }

      // online softmax in exp2 domain; per-lane scalar m/l (q = c).
      float tmax = sacc[0][0];
#pragma unroll
      for (int ni = 0; ni < 4; ni++)
#pragma unroll
        for (int r = 0; r < 4; r++) tmax = fmaxf(tmax, sacc[ni][r]);
      tmax = fmaxf(tmax, __shfl_xor(tmax, 16, 64));
      tmax = fmaxf(tmax, __shfl_xor(tmax, 32, 64));
      float mnew = fmaxf(m, tmax);
      float alpha = fexp2(m - mnew);  // exp2(-inf)=0 on first tile
      m = mnew;

      float psum = 0.f;
#pragma unroll
      for (int ni = 0; ni < 4; ni++) {
        float p0 = fexp2(sacc[ni][0] - mnew);
        float p1 = fexp2(sacc[ni][1] - mnew);
        float p2 = fexp2(sacc[ni][2] - mnew);
        float p3 = fexp2(sacc[ni][3] - mnew);
        psum += (p0 + p1) + (p2 + p3);
        uint2 pr = {pk2bf(p0, p1), pk2bf(p2, p3)};
        *(uint2*)&PbW[c * 72 + ni * 16 + quad * 4] = pr;
      }
      psum += __shfl_xor(psum, 16, 64);
      psum += __shfl_xor(psum, 32, 64);
      l = l * alpha + psum;

      // broadcast alpha to O's C-layout rows (alpha uniform across quads per c)
      float aR[4];
#pragma unroll
      for (int r = 0; r < 4; r++) aR[r] = __shfl(alpha, quad * 4 + r, 64);
#pragma unroll
      for (int ni = 0; ni < 4; ni++)
#pragma unroll
        for (int r = 0; r < 4; r++) o[ni][r] *= aR[r];

      // O += P V : A-frag = P rows (own-wave LDS region), B-frag = V^T rows.
#pragma unroll
      for (int ks = 0; ks < 2; ks++) {
        u16x8 pf = *(const u16x8*)&PbW[c * 72 + ks * 32 + quad * 8];
#pragma unroll
        for (int ni = 0; ni < 4; ni++) {
          const int slot = (ks * 4 + quad) ^ (c & 7);
          u16x8 vf = *(const u16x8*)&Vt[(ni * 16 + c) * 64 + slot * 8];
          o[ni] = mfma16(pf, vf, o[ni]);
        }
      }
    }

    float lR[4];
#pragma unroll
    for (int r = 0; r < 4; r++) lR[r] = frcp(__shfl(l, quad * 4 + r, 64));
#pragma unroll
    for (int ni = 0; ni < 4; ni++)
#pragma unroll
      for (int r = 0; r < 4; r++) {
        size_t row = (size_t)(qbase + quad * 4 + r);
        size_t col = (size_t)(h * DH + ni * 16 + c);
        Ob[row * D + col] = f2bf(o[ni][r] * lR[r]);
      }
  }
}

// ------------------------------------------------------------------- launcher
extern "C" void kernel_launch(void* const* d_in, const int* in_sizes, int n_in,
                              void* d_out, int out_size, void* d_ws, size_t ws_size,
                              hipStream_t stream) {
  const float* x  = (const float*)d_in[0];
  const float* Wq = (const float*)d_in[1];
  const float* Wk = (const float*)d_in[2];
  const float* Wv = (const float*)d_in[3];
  const float* Wo = (const float*)d_in[4];
  const float* rc = (const float*)d_in[5];
  const float* rs = (const float*)d_in[6];
  float* out = (float*)d_out;

  char* ws = (char*)d_ws;
  // bf16 workspace (bytes):
  //   xb    [0,8M)    x bf16; dead after QKV GEMM -> aliased by Ab
  //   wqkv  [8,20M)   fused QKV weights; dead after QKV GEMM -> VT reuses [8,10M)
  //   wob   [20,28M)
  //   qkvb  [28,40M)
  unsigned short* xb   = (unsigned short*)(ws);
  unsigned short* wqkv = (unsigned short*)(ws + (size_t)(8u  << 20));
  unsigned short* wob  = (unsigned short*)(ws + (size_t)(20u << 20));
  unsigned short* qkvb = (unsigned short*)(ws + (size_t)(28u << 20));
  unsigned short* Ab   = xb;                    // alias (x dead)
  unsigned short* VT   = wqkv;                  // alias (wqkv dead), 2 MB

  // 1) all fp32->bf16 conversions in one launch
  cvt_all<<<dim3(7168), 256, 0, stream>>>(x, Wq, Wk, Wv, Wo, xb, wqkv, wob);

  // 2) fused QKV projection: (2048 x 3072) = x @ Wqkv^T. grid 24x32=768 = 3/CU
  gemm_bt_bf16<true><<<dim3(NQKV / 128, T / 64), 256, 0, stream>>>(xb, wqkv, qkvb, NQKV, D);

  // 3) RoPE on Q,K (+exp2-domain Q scale) and V^T, one launch
  rope_tv<<<dim3(10240 + 256), 256, 0, stream>>>(qkvb, rc, rs, VT);

  // 4) attention: 8 kv-heads x 64 balanced tile-pairs = 512 blocks = 2/CU
  attn_kernel<<<dim3(HKV, T / 32), 256, 0, stream>>>(qkvb, VT, Ab);

  // 5) output projection: (2048 x 2048) = Ab @ Wo^T, fp32 out. 16x32=512 = 2/CU
  gemm_bt_bf16<false><<<dim3(D / 128, T / 64), 256, 0, stream>>>(Ab, wob, out, D, D);
}

// Round 7
// 223.296 us; speedup vs baseline: 2.8285x; 1.0224x over previous
//
#include <hip/hip_runtime.h>
#include <math.h>
#include <stdint.h>

// Problem constants (B=1)
static constexpr int T   = 2048;
static constexpr int D   = 2048;
static constexpr int HQ  = 32;
static constexpr int HKV = 8;
static constexpr int DH  = 64;
static constexpr int DKV = HKV * DH;       // 512
static constexpr int NQKV = D + 2 * DKV;   // 3072 fused QKV output width

typedef float f32x4 __attribute__((ext_vector_type(4)));
typedef __bf16 bf16x8 __attribute__((ext_vector_type(8)));
typedef __bf16 bf16x2 __attribute__((ext_vector_type(2)));
typedef unsigned short u16x8 __attribute__((ext_vector_type(8)));
typedef unsigned short u16x4 __attribute__((ext_vector_type(4)));

__device__ __forceinline__ unsigned short f2bf(float f) {
  union { float f; unsigned u; } v; v.f = f;
  unsigned u = v.u;
  return (unsigned short)((u + 0x7FFFu + ((u >> 16) & 1u)) >> 16);  // RNE
}
__device__ __forceinline__ float bf2f(unsigned short b) {
  union { unsigned u; float f; } v; v.u = ((unsigned)b) << 16;
  return v.f;
}
// packed f32x2 -> bf16x2 (single v_cvt_pk_bf16_f32 on gfx950)
__device__ __forceinline__ unsigned pk2bf(float a, float b) {
#if __has_builtin(__builtin_amdgcn_cvt_pk_bf16_f32)
  bf16x2 r = __builtin_amdgcn_cvt_pk_bf16_f32(a, b);
  return __builtin_bit_cast(unsigned, r);
#else
  return (unsigned)f2bf(a) | ((unsigned)f2bf(b) << 16);
#endif
}
__device__ __forceinline__ float fexp2(float x) {
#if __has_builtin(__builtin_amdgcn_exp2f)
  return __builtin_amdgcn_exp2f(x);  // raw v_exp_f32 (base-2)
#else
  return exp2f(x);
#endif
}
__device__ __forceinline__ float frcp(float x) {
#if __has_builtin(__builtin_amdgcn_rcpf)
  return __builtin_amdgcn_rcpf(x);   // v_rcp_f32, ~1ulp — fine for bf16 output
#else
  return 1.0f / x;
#endif
}
__device__ __forceinline__ f32x4 mfma16(u16x8 a, u16x8 b, f32x4 c) {
  return __builtin_amdgcn_mfma_f32_16x16x32_bf16(
      __builtin_bit_cast(bf16x8, a), __builtin_bit_cast(bf16x8, b), c, 0, 0, 0);
}
// async global->LDS, 16B per lane. LDS dest is wave-uniform base + lane*16.
__device__ __forceinline__ void gld16(const unsigned short* g, unsigned short* l) {
  __builtin_amdgcn_global_load_lds(
      (const __attribute__((address_space(1))) unsigned*)g,
      (__attribute__((address_space(3))) unsigned*)l, 16, 0, 0);
}

// --------------------------------------------- fused fp32 -> bf16 for all inputs
// One launch converts x, Wq, Wk, Wv, Wo. Segments in units of 2048-element
// blocks (256 thr x 8): x 2048 | Wq 2048 | Wk 512 | Wv 512 | Wo 2048 = 7168.
__global__ __launch_bounds__(256) void cvt_all(const float* __restrict__ x,
                                               const float* __restrict__ Wq,
                                               const float* __restrict__ Wk,
                                               const float* __restrict__ Wv,
                                               const float* __restrict__ Wo,
                                               unsigned short* __restrict__ xb,
                                               unsigned short* __restrict__ wqkv,
                                               unsigned short* __restrict__ wob) {
  int b = blockIdx.x;
  const float* src;
  unsigned short* dst;
  if (b < 2048)      { src = x;  dst = xb; }
  else if (b < 4096) { src = Wq; dst = wqkv;                          b -= 2048; }
  else if (b < 4608) { src = Wk; dst = wqkv + (size_t)D * D;          b -= 4096; }
  else if (b < 5120) { src = Wv; dst = wqkv + (size_t)(D + DKV) * D;  b -= 4608; }
  else               { src = Wo; dst = wob;                           b -= 5120; }
  size_t i = ((size_t)b * 256 + threadIdx.x) * 8;
  float4 a = *(const float4*)(src + i);
  float4 c = *(const float4*)(src + i + 4);
  uint4 r = {pk2bf(a.x, a.y), pk2bf(a.z, a.w), pk2bf(c.x, c.y), pk2bf(c.z, c.w)};
  *(uint4*)(dst + i) = r;
}

// ---------------------------------------------------- C[M,N] = A[M,K] @ Bt[N,K]^T
// 64M x 128N block tile, BK=128. LDS 48 KB -> 3 blocks/CU resident; co-resident
// blocks hide each other's barrier drains (m114). Async global_load_lds 16B
// with XOR swizzle: LDS row r, slot s holds source chunk s ^ (r&15); fragment
// read slot = (ks*4+quad) ^ c. 4 waves side-by-side in N; each 64Mx32N.
template <bool OUT_BF16>
__global__ __launch_bounds__(256) void gemm_bt_bf16(const unsigned short* __restrict__ A,
                                                    const unsigned short* __restrict__ Bt,
                                                    void* __restrict__ Cv,
                                                    int N, int K) {
  __shared__ alignas(16) unsigned short As[64 * 128];   // 16 KB
  __shared__ alignas(16) unsigned short Bs[128 * 128];  // 32 KB

  const int bn = blockIdx.x * 128, bm = blockIdx.y * 64;
  const int tid = threadIdx.x, w = tid >> 6, lane = tid & 63;
  const int c = lane & 15, quad = lane >> 4;

  const int r4 = lane >> 4, ch = lane & 15;
  const unsigned short* aRow = A + (size_t)(bm + w * 16 + r4) * K;
  const unsigned short* bRow = Bt + (size_t)(bn + w * 32 + r4) * K;
  unsigned short* AsW = As + (w * 16) * 128;
  unsigned short* BsW = Bs + (w * 32) * 128;

  f32x4 acc[4][2] = {};

  for (int k0 = 0; k0 < K; k0 += 128) {
#pragma unroll
    for (int j = 0; j < 4; j++) {
      const int sch = ch ^ ((j * 4 + r4) & 15);
      gld16(aRow + (size_t)(j * 4) * K + k0 + sch * 8, AsW + j * 4 * 128);
    }
#pragma unroll
    for (int j = 0; j < 8; j++) {
      const int sch = ch ^ ((j * 4 + r4) & 15);
      gld16(bRow + (size_t)(j * 4) * K + k0 + sch * 8, BsW + j * 4 * 128);
    }
    __syncthreads();  // drain vmcnt -> tiles complete

#pragma unroll
    for (int ks = 0; ks < 4; ks++) {
      const int slot = (ks * 4 + quad) ^ c;
      u16x8 a[4], b[2];
#pragma unroll
      for (int mi = 0; mi < 4; mi++)
        a[mi] = *(const u16x8*)&As[(mi * 16 + c) * 128 + slot * 8];
#pragma unroll
      for (int ni = 0; ni < 2; ni++)
        b[ni] = *(const u16x8*)&Bs[(w * 32 + ni * 16 + c) * 128 + slot * 8];
#pragma unroll
      for (int mi = 0; mi < 4; mi++)
#pragma unroll
        for (int ni = 0; ni < 2; ni++)
          acc[mi][ni] = mfma16(a[mi], b[ni], acc[mi][ni]);
    }
    __syncthreads();  // protect LDS from next-iter overwrite
  }

#pragma unroll
  for (int mi = 0; mi < 4; mi++)
#pragma unroll
    for (int ni = 0; ni < 2; ni++)
#pragma unroll
      for (int r = 0; r < 4; r++) {
        size_t row = (size_t)(bm + mi * 16 + quad * 4 + r);
        size_t col = (size_t)(bn + w * 32 + ni * 16 + c);
        if (OUT_BF16)
          ((unsigned short*)Cv)[row * N + col] = f2bf(acc[mi][ni][r]);
        else
          ((float*)Cv)[row * N + col] = acc[mi][ni][r];
      }
}

// ----------------------------------------- fused RoPE (Q,K) + V transpose
// Blocks [0, 10240): rope in-place on qkvb; Q pre-scaled by log2(e)/8 so
// attention scores are in the exp2 domain. Blocks [10240, 10496): 64x64
// transpose of V (T,dkv)->(dkv,T), pad-65 LDS, conflict-free.
__global__ __launch_bounds__(256) void rope_tv(unsigned short* __restrict__ QKV,
                                               const float* __restrict__ cosb,
                                               const float* __restrict__ sinb,
                                               unsigned short* __restrict__ VT) {
  const int QP = T * HQ * (DH / 2);   // 2097152
  if (blockIdx.x < 10240) {
    int idx = blockIdx.x * 256 + threadIdx.x;
    unsigned short* p;
    int t, i;
    float sc;
    if (idx < QP) {
      t = idx / (HQ * DH / 2);
      int rem = idx - t * (HQ * DH / 2);
      i = rem & 31;
      p = QKV + (size_t)t * NQKV + rem * 2;
      sc = 0.125f * 1.44269504088896340736f;  // (1/sqrt(DH)) * log2(e)
    } else {
      int j = idx - QP;
      t = j / (HKV * DH / 2);
      int rem = j - t * (HKV * DH / 2);
      i = rem & 31;
      p = QKV + (size_t)t * NQKV + D + rem * 2;
      sc = 1.0f;
    }
    float x0 = bf2f(p[0]), x1 = bf2f(p[1]);
    float cs = cosb[t * 32 + i], sn = sinb[t * 32 + i];
    *(unsigned*)p = pk2bf((x0 * cs - x1 * sn) * sc, (x0 * sn + x1 * cs) * sc);
  } else {
    __shared__ unsigned short Ts[64][65];
    const int bid = blockIdx.x - 10240;
    const int tb = bid & 31, db = bid >> 5;   // tb: T/64, db: DKV/64
    const int tid = threadIdx.x;
    const int r = tid >> 2, c0 = (tid & 3) * 16;
    const unsigned short* src = QKV + (size_t)(tb * 64 + r) * NQKV + (D + DKV) + db * 64 + c0;
    *(u16x8*)&Ts[r][c0]     = *(const u16x8*)src;
    *(u16x8*)&Ts[r][c0 + 8] = *(const u16x8*)(src + 8);
    __syncthreads();
    u16x8 a, b;
#pragma unroll
    for (int j = 0; j < 8; j++) a[j] = Ts[c0 + j][r];
#pragma unroll
    for (int j = 0; j < 8; j++) b[j] = Ts[c0 + 8 + j][r];
    unsigned short* dst = VT + (size_t)(db * 64 + r) * T + tb * 64 + c0;
    *(u16x8*)dst = a;
    *(u16x8*)(dst + 8) = b;
  }
}

// ------------------------------------------------------------------- attention
// Flash-style, S^T formulation, GQA-grouped, 128-key tiles. Block = (kv-head,
// 16-row q-tile); 4 waves = the 4 q-heads sharing the kv-head -> K/V staged
// once per group. One q-row per lane-c: m/l/alpha per-lane scalars; the
// per-tile fixed costs (max-reduce, alpha broadcast, rescale, l-update,
// barriers) are paid once per 128 keys instead of per 64. Grid 8x128 = 1024
// blocks, LPT order; LDS ~50 KB -> 3 blocks/CU.
__global__ __launch_bounds__(256) void attn_kernel(const unsigned short* __restrict__ QKV,
                                                   const unsigned short* __restrict__ VT,
                                                   unsigned short* __restrict__ Ob) {
  const int kh = blockIdx.x;                          // kv head 0..7
  const int qt = (int)(gridDim.y - 1 - blockIdx.y);   // LPT: long tiles first
  const int qbase = qt * 16;
  const int tid = threadIdx.x, w = tid >> 6, lane = tid & 63;
  const int c = lane & 15, quad = lane >> 4;
  const int h = kh * 4 + w;                           // this wave's q head

  __shared__ alignas(16) unsigned short Kt[128 * 64];      // (key, dh) swizzled, 16 KB
  __shared__ alignas(16) unsigned short Vt[64 * 128];      // (dh, key) swizzled, 16 KB
  __shared__ alignas(16) unsigned short Pb[4 * 16 * 136];  // per-wave P (q, key), 17 KB

  unsigned short* PbW = Pb + w * 16 * 136;

  // Q as B-fragments: q-row qbase+c, head h (pre-scaled by log2e/8 in rope)
  u16x8 qf[2];
  {
    const unsigned short* qp = QKV + (size_t)(qbase + c) * NQKV + h * DH + quad * 8;
    qf[0] = *(const u16x8*)qp;
    qf[1] = *(const u16x8*)(qp + 32);
  }

  // K staging: wave w stages Kt rows [w*32, w*32+32): 4 gld16 x 8 rows.
  // lane -> row8 = lane>>3, slot = lane&7 receives source chunk slot^(row&7).
  const int sr8 = lane >> 3;
  const int sc8 = (lane & 7) ^ sr8;
  const unsigned short* kgBase = QKV + D + (size_t)(w * 32 + sr8) * NQKV + kh * DH + sc8 * 8;
  unsigned short* KtW = Kt + (w * 32) * 64;
  // V staging: wave w stages Vt rows [w*16, w*16+16): 4 gld16 x 4 rows.
  // lane -> row4 = lane>>4, slot = lane&15 receives chunk slot^(row&15).
  const int sr4 = lane >> 4, ch16 = lane & 15;
  const unsigned short* vgRow = VT + (size_t)(kh * DH + w * 16 + sr4) * T;
  unsigned short* VtW = Vt + (w * 16) * 128;

  f32x4 o[4] = {};
  float m = -INFINITY, l = 0.f;

  const int nFull = qt >> 3;  // diagonal 128-key tile index
  for (int st = 0; st <= nFull; st++) {
    __syncthreads();  // previous-iter reads done before overwrite
#pragma unroll
    for (int j = 0; j < 4; j++) {
      gld16(kgBase + ((size_t)st * 128 + (size_t)j * 8) * NQKV, KtW + j * 8 * 64);
      const int sch = ch16 ^ ((j * 4 + sr4) & 15);
      gld16(vgRow + (size_t)(j * 4) * T + st * 128 + sch * 8, VtW + j * 4 * 128);
    }
    __syncthreads();  // vmcnt drained -> tiles complete

    // S^T = K Q^T : A-frag = K rows, B-frag = Q. D[key=ni*16+quad*4+r][q=c].
    f32x4 sacc[8] = {};
#pragma unroll
    for (int ks = 0; ks < 2; ks++) {
#pragma unroll
      for (int ni = 0; ni < 8; ni++) {
        const int slot = (ks * 4 + quad) ^ (c & 7);
        u16x8 kf = *(const u16x8*)&Kt[(ni * 16 + c) * 64 + slot * 8];
        sacc[ni] = mfma16(kf, qf[ks], sacc[ni]);
      }
    }

    // causal mask: only diagonal tile (uniform branch)
    if (st == nFull) {
      const int qrow = qbase + c;
#pragma unroll
      for (int ni = 0; ni < 8; ni++)
#pragma unroll
        for (int r = 0; r < 4; r++) {
          int key = st * 128 + ni * 16 + quad * 4 + r;
          if (key > qrow) sacc[ni][r] = -INFINITY;
        }
    }

    // online softmax in exp2 domain; per-lane scalar m/l (q = c).
    float tmax = sacc[0][0];
#pragma unroll
    for (int ni = 0; ni < 8; ni++)
#pragma unroll
      for (int r = 0; r < 4; r++) tmax = fmaxf(tmax, sacc[ni][r]);
    tmax = fmaxf(tmax, __shfl_xor(tmax, 16, 64));
    tmax = fmaxf(tmax, __shfl_xor(tmax, 32, 64));
    float mnew = fmaxf(m, tmax);
    float alpha = fexp2(m - mnew);  // exp2(-inf)=0 on first tile
    m = mnew;

    float psum = 0.f;
#pragma unroll
    for (int ni = 0; ni < 8; ni++) {
      float p0 = fexp2(sacc[ni][0] - mnew);
      float p1 = fexp2(sacc[ni][1] - mnew);
      float p2 = fexp2(sacc[ni][2] - mnew);
      float p3 = fexp2(sacc[ni][3] - mnew);
      psum += (p0 + p1) + (p2 + p3);
      uint2 pr = {pk2bf(p0, p1), pk2bf(p2, p3)};
      // P^T (C-layout) -> P (q,key) rows: lane writes row c
      *(uint2*)&PbW[c * 136 + ni * 16 + quad * 4] = pr;
    }
    psum += __shfl_xor(psum, 16, 64);
    psum += __shfl_xor(psum, 32, 64);
    l = l * alpha + psum;

    // broadcast alpha to O's C-layout rows (alpha uniform across quads per c)
    float aR[4];
#pragma unroll
    for (int r = 0; r < 4; r++) aR[r] = __shfl(alpha, quad * 4 + r, 64);
#pragma unroll
    for (int ni = 0; ni < 4; ni++)
#pragma unroll
      for (int r = 0; r < 4; r++) o[ni][r] *= aR[r];

    // O += P V : A-frag = P rows (own-wave LDS region), B-frag = V^T rows.
#pragma unroll
    for (int ks = 0; ks < 4; ks++) {
      u16x8 pf = *(const u16x8*)&PbW[c * 136 + ks * 32 + quad * 8];
#pragma unroll
      for (int ni = 0; ni < 4; ni++) {
        const int slot = (ks * 4 + quad) ^ c;
        u16x8 vf = *(const u16x8*)&Vt[(ni * 16 + c) * 128 + slot * 8];
        o[ni] = mfma16(pf, vf, o[ni]);
      }
    }
  }

  float lR[4];
#pragma unroll
  for (int r = 0; r < 4; r++) lR[r] = frcp(__shfl(l, quad * 4 + r, 64));
#pragma unroll
  for (int ni = 0; ni < 4; ni++)
#pragma unroll
    for (int r = 0; r < 4; r++) {
      size_t row = (size_t)(qbase + quad * 4 + r);
      size_t col = (size_t)(h * DH + ni * 16 + c);
      Ob[row * D + col] = f2bf(o[ni][r] * lR[r]);
    }
}

// ------------------------------------------------------------------- launcher
extern "C" void kernel_launch(void* const* d_in, const int* in_sizes, int n_in,
                              void* d_out, int out_size, void* d_ws, size_t ws_size,
                              hipStream_t stream) {
  const float* x  = (const float*)d_in[0];
  const float* Wq = (const float*)d_in[1];
  const float* Wk = (const float*)d_in[2];
  const float* Wv = (const float*)d_in[3];
  const float* Wo = (const float*)d_in[4];
  const float* rc = (const float*)d_in[5];
  const float* rs = (const float*)d_in[6];
  float* out = (float*)d_out;

  char* ws = (char*)d_ws;
  // bf16 workspace (bytes):
  //   xb    [0,8M)    x bf16; dead after QKV GEMM -> aliased by Ab
  //   wqkv  [8,20M)   fused QKV weights; dead after QKV GEMM -> VT reuses [8,10M)
  //   wob   [20,28M)
  //   qkvb  [28,40M)
  unsigned short* xb   = (unsigned short*)(ws);
  unsigned short* wqkv = (unsigned short*)(ws + (size_t)(8u  << 20));
  unsigned short* wob  = (unsigned short*)(ws + (size_t)(20u << 20));
  unsigned short* qkvb = (unsigned short*)(ws + (size_t)(28u << 20));
  unsigned short* Ab   = xb;                    // alias (x dead)
  unsigned short* VT   = wqkv;                  // alias (wqkv dead), 2 MB

  // 1) all fp32->bf16 conversions in one launch
  cvt_all<<<dim3(7168), 256, 0, stream>>>(x, Wq, Wk, Wv, Wo, xb, wqkv, wob);

  // 2) fused QKV projection: (2048 x 3072) = x @ Wqkv^T. grid 24x32=768 = 3/CU
  gemm_bt_bf16<true><<<dim3(NQKV / 128, T / 64), 256, 0, stream>>>(xb, wqkv, qkvb, NQKV, D);

  // 3) RoPE on Q,K (+exp2-domain Q scale) and V^T, one launch
  rope_tv<<<dim3(10240 + 256), 256, 0, stream>>>(qkvb, rc, rs, VT);

  // 4) attention: 8 kv-heads x 128 q-tiles (LPT) = 1024 blocks, 128-key iters
  attn_kernel<<<dim3(HKV, T / 16), 256, 0, stream>>>(qkvb, VT, Ab);

  // 5) output projection: (2048 x 2048) = Ab @ Wo^T, fp32 out. 16x32=512 = 2/CU
  gemm_bt_bf16<false><<<dim3(D / 128, T / 64), 256, 0, stream>>>(Ab, wob, out, D, D);
}